// Round 12
// baseline (1033.023 us; speedup 1.0000x reference)
//
#include <hip/hip_runtime.h>
#include <math.h>

typedef unsigned short u16;
typedef unsigned int u32;
typedef __attribute__((ext_vector_type(8))) short bf16x8;
typedef __attribute__((ext_vector_type(4))) float f32x4;

#define Bx 1024
#define Lx 200
#define Dx 128
#define FFx 512
#define Mx (Bx*Lx)
#define PVP 232   // P/V^T LDS row stride (u16)
#define TSP 40    // ts row stride (u16): 32 cols + 8 pad; 2-way pattern (free)

__device__ __forceinline__ u16 f2bf(float f) {
  u32 u = __float_as_uint(f);
  u32 r = (u + 0x7fffu + ((u >> 16) & 1u)) >> 16;
  return (u16)r;
}

// fast GELU: tanh form, v*sigmoid(1.59577v + 0.0713548 v^3).
// |err| vs exact erf-gelu < 1e-4 for |v|<2 (pre-act sigma~0.23) — below bf16 eps.
__device__ __forceinline__ float gelu_f(float v) {
  float z = v * fmaf(v * v, 0.0713548163f, 1.5957691216f);
  float e = __expf(-z);
  return v * __builtin_amdgcn_rcpf(1.0f + e);
}

union BFCV { u32 u[4]; bf16x8 h; };

// ---------------- merged weight convert: fp32 [K][N] -> bf16 fragment order -------
// One launch for all 13 weight tensors. dst: [n_tile][k_step][lane][8],
// val = src[kst*32 + (lane>>4)*8 + j][ntile*16 + (lane&15)]
struct CvtJobs {
  const float* src[13];
  u16* dst[13];
  int N[13];
  int ks[13];
  int bstart[14];
};

__global__ void k_cvt_all(CvtJobs J) {
  const int b = blockIdx.x;
  int j = 0;
  #pragma unroll 1
  while (b >= J.bstart[j + 1]) ++j;          // uniform per block (scalar)
  const float* __restrict__ src = J.src[j];
  u16* __restrict__ dst = J.dst[j];
  const int N = J.N[j], k_steps = J.ks[j];
  int id = (b - J.bstart[j]) * 256 + threadIdx.x;
  int lane = id & 63;
  int rest = id >> 6;
  int kst = rest % k_steps;
  int ntile = rest / k_steps;
  int n = ntile * 16 + (lane & 15);
  int kb = kst * 32 + ((lane >> 4) << 3);
  const float* sp = src + (size_t)kb * N + n;
  u32 w[4];
  #pragma unroll
  for (int jj = 0; jj < 4; ++jj) {
    u32 lo = f2bf(sp[(size_t)(2 * jj) * N]);
    u32 hi = f2bf(sp[(size_t)(2 * jj + 1) * N]);
    w[jj] = lo | (hi << 16);
  }
  ((uint4*)dst)[id] = make_uint4(w[0], w[1], w[2], w[3]);
}

// ---------------- embedding: x = tok[seq] + pos ----------------
__global__ void k_embed(const int* __restrict__ seq, const float* __restrict__ tok,
                        const float* __restrict__ pos, float* __restrict__ x) {
  const int i = blockIdx.x * 256 + threadIdx.x;
  const int row = i >> 5, c = i & 31;
  const int t = seq[row];
  const int l = row % Lx;
  const float4 a = ((const float4*)tok)[(size_t)t * 32 + c];
  const float4 p = ((const float4*)pos)[l * 32 + c];
  ((float4*)x)[i] = make_float4(a.x + p.x, a.y + p.y, a.z + p.z, a.w + p.w);
}

// ---- register layernorm: lane (quad,l15) owns one row; row stats reduced across
// the 4 quad-lanes via shfl_xor(16/32). Packs af[] A-frags.
__device__ __forceinline__ void reg_ln(const float* __restrict__ xr,
                                       const float* __restrict__ ln_w,
                                       const float* __restrict__ ln_b,
                                       int quad, bf16x8 af[4]) {
  float v[32];
  float s = 0.f, sq = 0.f;
  #pragma unroll
  for (int kst = 0; kst < 4; ++kst) {
    float4 a = *(const float4*)(xr + kst * 32);
    float4 b = *(const float4*)(xr + kst * 32 + 4);
    v[kst * 8 + 0] = a.x; v[kst * 8 + 1] = a.y; v[kst * 8 + 2] = a.z; v[kst * 8 + 3] = a.w;
    v[kst * 8 + 4] = b.x; v[kst * 8 + 5] = b.y; v[kst * 8 + 6] = b.z; v[kst * 8 + 7] = b.w;
  }
  #pragma unroll
  for (int i = 0; i < 32; ++i) { s += v[i]; sq = fmaf(v[i], v[i], sq); }
  s  += __shfl_xor(s, 16);  s  += __shfl_xor(s, 32);
  sq += __shfl_xor(sq, 16); sq += __shfl_xor(sq, 32);
  float mu = s * 0.0078125f;
  float rr = rsqrtf(fmaf(-mu, mu, sq * 0.0078125f) + 1e-5f);
  #pragma unroll
  for (int kst = 0; kst < 4; ++kst) {
    const float* lwp = ln_w + kst * 32 + quad * 8;
    const float* lbp = ln_b + kst * 32 + quad * 8;
    float4 lw0 = *(const float4*)(lwp);
    float4 lw1 = *(const float4*)(lwp + 4);
    float4 lb0 = *(const float4*)(lbp);
    float4 lb1 = *(const float4*)(lbp + 4);
    float hw[8] = {lw0.x, lw0.y, lw0.z, lw0.w, lw1.x, lw1.y, lw1.z, lw1.w};
    float hb[8] = {lb0.x, lb0.y, lb0.z, lb0.w, lb1.x, lb1.y, lb1.z, lb1.w};
    BFCV cv;
    #pragma unroll
    for (int j = 0; j < 4; ++j) {
      float h0 = fmaf((v[kst * 8 + 2 * j]     - mu) * rr, hw[2 * j],     hb[2 * j]);
      float h1 = fmaf((v[kst * 8 + 2 * j + 1] - mu) * rr, hw[2 * j + 1], hb[2 * j + 1]);
      cv.u[j] = (u32)f2bf(h0) | ((u32)f2bf(h1) << 16);
    }
    af[kst] = cv.h;
  }
}

// ---------------- fused LN + QKV GEMM (MFMA), register LN, no LDS ----------------
__global__ __launch_bounds__(256, 4)
void k_qkv(const float* __restrict__ x, const float* __restrict__ ln_w,
           const float* __restrict__ ln_b, const u16* __restrict__ Wqkvs,
           const float* __restrict__ bq, const float* __restrict__ bk,
           const float* __restrict__ bv,
           u16* __restrict__ qo, u16* __restrict__ ko, u16* __restrict__ vo) {
  const int tid = threadIdx.x;
  const int row0 = blockIdx.x * 64;
  const int lane = tid & 63, wv = tid >> 6;
  const int l15 = lane & 15, quad = lane >> 4;
  const int m0 = wv * 16;

  bf16x8 af[4];
  reg_ln(x + (size_t)(row0 + m0 + l15) * Dx + quad * 8, ln_w, ln_b, quad, af);

  int bl[4], ll[4];
  #pragma unroll
  for (int r = 0; r < 4; ++r) {
    int gr = row0 + m0 + quad * 4 + r;
    bl[r] = gr / 200;
    ll[r] = gr - bl[r] * 200;
  }

  const float scale = 0.17677669529663687f;
  #pragma unroll
  for (int nt = 0; nt < 24; ++nt) {
    f32x4 acc = (f32x4){0.f, 0.f, 0.f, 0.f};
    const u16* wb = Wqkvs + ((size_t)(nt * 4) * 64 + lane) * 8;
    #pragma unroll
    for (int kst = 0; kst < 4; ++kst) {
      bf16x8 bfr = *(const bf16x8*)(wb + kst * 64 * 8);
      acc = __builtin_amdgcn_mfma_f32_16x16x32_bf16(af[kst], bfr, acc, 0, 0, 0);
    }
    const int col = (nt & 7) * 16 + l15;
    const int head = col >> 5, dk = col & 31;
    if (nt < 8) {
      float bb = bq[col];
      #pragma unroll
      for (int r = 0; r < 4; ++r)
        qo[((size_t)(bl[r] * 4 + head) * 200 + ll[r]) * 32 + dk] = f2bf((acc[r] + bb) * scale);
    } else if (nt < 16) {
      float bb = bk[col];
      #pragma unroll
      for (int r = 0; r < 4; ++r)
        ko[((size_t)(bl[r] * 4 + head) * 200 + ll[r]) * 32 + dk] = f2bf(acc[r] + bb);
    } else {
      float bb = bv[col];
      #pragma unroll
      for (int r = 0; r < 4; ++r)
        vo[((size_t)(bl[r] * 4 + head) * 200 + ll[r]) * 32 + dk] = f2bf(acc[r] + bb);
    }
  }
}

// ---------------- MFMA attention: one block per (b_local, head) ----------------
__global__ __launch_bounds__(256, 3)
void k_attn2(const u16* __restrict__ q, const u16* __restrict__ k,
             const u16* __restrict__ v, const int* __restrict__ seq,
             u16* __restrict__ attn) {
  __shared__ float smask[224];
  __shared__ __align__(16) u16 vt[32 * PVP];
  __shared__ __align__(16) u16 Pb[4][16 * PVP];
  const int tid = threadIdx.x;
  const int bl = blockIdx.x >> 2, head = blockIdx.x & 3;
  const int bh = blockIdx.x;
  const int lane = tid & 63, wv = tid >> 6;
  const int l15 = lane & 15, quad = lane >> 4;

  if (tid < 224)
    smask[tid] = (tid < 200 && seq[bl * 200 + tid] > 0) ? 0.f : -1e9f;
  // stage V^T into LDS: vt[dk][l]
  #pragma unroll 1
  for (int e = tid; e < 800; e += 256) {
    int l = e >> 2, g = (e & 3) * 8;
    uint4 pv = *(const uint4*)(v + ((size_t)bh * 200 + l) * 32 + g);
    const u16* pw = (const u16*)&pv;
    #pragma unroll
    for (int j = 0; j < 8; ++j) vt[(g + j) * PVP + l] = pw[j];
  }
  // zero V^T pad cols [200,232)
  #pragma unroll 1
  for (int e = tid; e < 1024; e += 256) {
    int rr = e >> 5, cc = 200 + (e & 31);
    vt[rr * PVP + cc] = 0;
  }
  __syncthreads();

  float msk[14];
  #pragma unroll
  for (int nt = 0; nt < 14; ++nt) msk[nt] = smask[nt * 16 + l15];

  const u16* qbase = q + (size_t)bh * 200 * 32;
  const u16* kbase = k + (size_t)bh * 200 * 32;
  u16* Pw = Pb[wv];

  #pragma unroll 1
  for (int mt = wv; mt < 13; mt += 4) {
    bf16x8 qf = *(const bf16x8*)(qbase + (mt * 16 + l15) * 32 + quad * 8);
    f32x4 s[14];
    #pragma unroll
    for (int nt = 0; nt < 14; ++nt) {
      bf16x8 kf = *(const bf16x8*)(kbase + (nt * 16 + l15) * 32 + quad * 8);
      s[nt] = __builtin_amdgcn_mfma_f32_16x16x32_bf16(qf, kf, (f32x4){0.f, 0.f, 0.f, 0.f}, 0, 0, 0);
    }
    // mask + row max
    float rmax[4] = {-1e30f, -1e30f, -1e30f, -1e30f};
    #pragma unroll
    for (int nt = 0; nt < 14; ++nt) {
      #pragma unroll
      for (int r = 0; r < 4; ++r) {
        s[nt][r] += msk[nt];
        rmax[r] = fmaxf(rmax[r], s[nt][r]);
      }
    }
    #pragma unroll
    for (int m = 1; m < 16; m <<= 1) {
      #pragma unroll
      for (int r = 0; r < 4; ++r) rmax[r] = fmaxf(rmax[r], __shfl_xor(rmax[r], m));
    }
    // exp + row sum
    float rsum[4] = {0.f, 0.f, 0.f, 0.f};
    #pragma unroll
    for (int nt = 0; nt < 14; ++nt) {
      #pragma unroll
      for (int r = 0; r < 4; ++r) {
        float p = __expf(s[nt][r] - rmax[r]);
        s[nt][r] = p;
        rsum[r] += p;
      }
    }
    #pragma unroll
    for (int m = 1; m < 16; m <<= 1) {
      #pragma unroll
      for (int r = 0; r < 4; ++r) rsum[r] += __shfl_xor(rsum[r], m);
    }
    float inv[4];
    #pragma unroll
    for (int r = 0; r < 4; ++r) inv[r] = 1.0f / rsum[r];
    // P -> wave-private LDS (bf16, unnormalized)
    #pragma unroll
    for (int nt = 0; nt < 14; ++nt) {
      #pragma unroll
      for (int r = 0; r < 4; ++r)
        Pw[(quad * 4 + r) * PVP + nt * 16 + l15] = f2bf(s[nt][r]);
    }
    __asm__ __volatile__("s_waitcnt lgkmcnt(0)" ::: "memory");
    // O = P @ V
    f32x4 o0 = (f32x4){0.f, 0.f, 0.f, 0.f}, o1 = (f32x4){0.f, 0.f, 0.f, 0.f};
    #pragma unroll
    for (int kst = 0; kst < 7; ++kst) {
      bf16x8 pf  = *(const bf16x8*)&Pw[l15 * PVP + kst * 32 + quad * 8];
      bf16x8 vf0 = *(const bf16x8*)&vt[l15 * PVP + kst * 32 + quad * 8];
      bf16x8 vf1 = *(const bf16x8*)&vt[(16 + l15) * PVP + kst * 32 + quad * 8];
      o0 = __builtin_amdgcn_mfma_f32_16x16x32_bf16(pf, vf0, o0, 0, 0, 0);
      o1 = __builtin_amdgcn_mfma_f32_16x16x32_bf16(pf, vf1, o1, 0, 0, 0);
    }
    #pragma unroll
    for (int r = 0; r < 4; ++r) {
      int row = mt * 16 + quad * 4 + r;
      if (row < 200) {
        u16* op = attn + ((size_t)bl * 200 + row) * 128 + head * 32;
        op[l15]      = f2bf(o0[r] * inv[r]);
        op[16 + l15] = f2bf(o1[r] * inv[r]);
      }
    }
  }
}

// ---------------- O-projection + residual (MFMA): x += a @ Wo + bo ----------------
// (fallback path only — used when workspace can't hold a full-size ab buffer)
__global__ __launch_bounds__(256, 4)
void k_oproj(const u16* __restrict__ a, const u16* __restrict__ Wos,
             const float* __restrict__ bo, float* __restrict__ x) {
  const int tid = threadIdx.x;
  const int lane = tid & 63, wv = tid >> 6;
  const int l15 = lane & 15, quad = lane >> 4;
  const size_t m0 = (size_t)blockIdx.x * 64 + wv * 16;
  f32x4 acc[8];
  #pragma unroll
  for (int i = 0; i < 8; ++i) acc[i] = (f32x4){0.f, 0.f, 0.f, 0.f};
  #pragma unroll
  for (int kst = 0; kst < 4; ++kst) {
    bf16x8 af = *(const bf16x8*)(a + (m0 + l15) * Dx + kst * 32 + quad * 8);
    const u16* wb = Wos + (kst * 64 + lane) * 8;
    #pragma unroll
    for (int nt = 0; nt < 8; ++nt) {
      bf16x8 bf = *(const bf16x8*)(wb + nt * (4 * 64 * 8));
      acc[nt] = __builtin_amdgcn_mfma_f32_16x16x32_bf16(af, bf, acc[nt], 0, 0, 0);
    }
  }
  #pragma unroll
  for (int nt = 0; nt < 8; ++nt) {
    int col = nt * 16 + l15;
    float bb = bo[col];
    #pragma unroll
    for (int r = 0; r < 4; ++r) {
      size_t idx = (m0 + quad * 4 + r) * Dx + col;
      x[idx] += acc[nt][r] + bb;
    }
  }
}

// ------- fused [oproj + residual +] LN + FFN (MFMA) -------
// When abp != nullptr: phase 0 computes x_new = x + ab@Wo + bo for the block's own
// 64 rows, INITIALIZING acc2 with x_new (MFMA C-in rides through the W2 GEMM, so
// the epilogue is a plain store x = acc2 + b2 — no extra registers, no RMW read).
// x_new is stored to global (L2-hot) so LN can re-read it in row-distribution after
// one barrier. Eliminates the k_oproj kernel + ~260 MB HBM x-traffic per layer.
// Otherwise identical to the verified r11 k_ffn (139.6 us).
__global__ __launch_bounds__(256, 4)
void k_ffn(float* __restrict__ x, const u16* __restrict__ abp,
           const u16* __restrict__ Wos, const float* __restrict__ bo,
           const float* __restrict__ ln_w, const float* __restrict__ ln_b,
           const u16* __restrict__ W1s, const float* __restrict__ b1,
           const u16* __restrict__ W2s, const float* __restrict__ b2) {
  __shared__ __align__(16) u16 smem[2560 + 8192 + 8192];
  u16* ts  = smem;            // [64][TSP=40]
  u16* w1b = smem + 2560;     // 2 x 4096 u16 (8 KB each)
  u16* w2b = smem + 10752;    // 2 x 4096 u16
  const int tid = threadIdx.x;
  const size_t row0 = (size_t)blockIdx.x * 64;
  const int lane = tid & 63, wv = tid >> 6;           // wv in [0,4)
  const int l15 = lane & 15, quad = lane >> 4;
  const int m0 = wv * 16;
  const int nt0 = tid >> 6, off = tid & 63;           // staging: 2 x 1KB pieces/thread

  f32x4 acc2[8];
  #pragma unroll
  for (int i = 0; i < 8; ++i) acc2[i] = (f32x4){0.f, 0.f, 0.f, 0.f};

  // ---- phase 0: oproj + residual into acc2; x_new stored for LN re-read ----
  if (abp) {
    #pragma unroll
    for (int kst = 0; kst < 4; ++kst) {
      bf16x8 abf = *(const bf16x8*)(abp + (row0 + m0 + l15) * (size_t)Dx + kst * 32 + quad * 8);
      const u16* wb = Wos + (kst * 64 + lane) * 8;
      #pragma unroll
      for (int nt = 0; nt < 8; ++nt) {
        bf16x8 wf = *(const bf16x8*)(wb + nt * (4 * 64 * 8));
        acc2[nt] = __builtin_amdgcn_mfma_f32_16x16x32_bf16(abf, wf, acc2[nt], 0, 0, 0);
      }
    }
    #pragma unroll
    for (int nt = 0; nt < 8; ++nt) {
      int col = nt * 16 + l15;
      float bb = bo[col];
      #pragma unroll
      for (int r = 0; r < 4; ++r) {
        size_t idx = (row0 + m0 + quad * 4 + r) * Dx + col;
        float xn = x[idx] + acc2[nt][r] + bb;
        acc2[nt][r] = xn;
        x[idx] = xn;
      }
    }
  }

  // prologue: stage W1(ch0,kst0) and W2(ch0,p0) — 8 KB each, 2 uint4/thread
  ((uint4*)w1b)[tid]       = ((const uint4*)(W1s + (size_t)(nt0 * 4) * 512))[off];
  ((uint4*)w1b)[tid + 256] = ((const uint4*)(W1s + (size_t)((nt0 + 4) * 4) * 512))[off];
  ((uint4*)w2b)[tid]       = ((const uint4*)(W2s + (size_t)(nt0 * 16) * 512))[off];
  ((uint4*)w2b)[tid + 256] = ((const uint4*)(W2s + (size_t)((nt0 + 4) * 16) * 512))[off];
  __syncthreads();   // drains x_new stores (vmcnt) + staging ds_writes (lgkm)

  bf16x8 af[4];
  reg_ln(x + (row0 + m0 + l15) * (size_t)Dx + quad * 8, ln_w, ln_b, quad, af);

  #pragma unroll 1
  for (int ch = 0; ch < 4; ++ch) {
    // ---- GEMM1: 4 kst phases, dbuf, async-split staging ----
    f32x4 acc1[8];
    #pragma unroll
    for (int i = 0; i < 8; ++i) acc1[i] = (f32x4){0.f, 0.f, 0.f, 0.f};
    #pragma unroll
    for (int kst = 0; kst < 4; ++kst) {
      uint4 s0, s1;
      if (kst < 3) {
        s0 = ((const uint4*)(W1s + (size_t)((ch * 8 + nt0) * 4 + kst + 1) * 512))[off];
        s1 = ((const uint4*)(W1s + (size_t)((ch * 8 + nt0 + 4) * 4 + kst + 1) * 512))[off];
      }
      const u16* wb = w1b + (kst & 1) * 4096;
      #pragma unroll
      for (int nt = 0; nt < 8; ++nt) {
        bf16x8 bfr = *(const bf16x8*)&wb[nt * 512 + lane * 8];
        acc1[nt] = __builtin_amdgcn_mfma_f32_16x16x32_bf16(af[kst], bfr, acc1[nt], 0, 0, 0);
      }
      if (kst < 3) {
        uint4* d = (uint4*)(w1b + ((kst + 1) & 1) * 4096);
        d[tid] = s0; d[tid + 256] = s1;
      }
      __syncthreads();
    }
    // ---- GELU + GEMM2: 4 p phases; gelu slice p feeds kst p ----
    #pragma unroll
    for (int p = 0; p < 4; ++p) {
      uint4 s0, s1, t0, t1;
      const bool s2  = (p < 3);
      const bool s1n = (p == 3) && (ch < 3);
      if (s2) {
        s0 = ((const uint4*)(W2s + (size_t)(nt0 * 16 + ch * 4 + p + 1) * 512))[off];
        s1 = ((const uint4*)(W2s + (size_t)((nt0 + 4) * 16 + ch * 4 + p + 1) * 512))[off];
      }
      if (s1n) {
        s0 = ((const uint4*)(W1s + (size_t)(((ch + 1) * 8 + nt0) * 4) * 512))[off];
        s1 = ((const uint4*)(W1s + (size_t)(((ch + 1) * 8 + nt0 + 4) * 4) * 512))[off];
        t0 = ((const uint4*)(W2s + (size_t)(nt0 * 16 + (ch + 1) * 4) * 512))[off];
        t1 = ((const uint4*)(W2s + (size_t)((nt0 + 4) * 16 + (ch + 1) * 4) * 512))[off];
      }
      // GELU slice p (cols p*32..p*32+32 of this ch) -> ts, wave-private rows
      #pragma unroll
      for (int q2 = 0; q2 < 2; ++q2) {
        const int ntg = 2 * p + q2;
        float bb = b1[ch * 128 + ntg * 16 + l15];
        #pragma unroll
        for (int r = 0; r < 4; ++r)
          ts[(m0 + quad * 4 + r) * TSP + q2 * 16 + l15] =
              f2bf(gelu_f(acc1[ntg][r] + bb));
      }
      __asm__ __volatile__("s_waitcnt lgkmcnt(0)" ::: "memory");
      bf16x8 tf = *(const bf16x8*)&ts[(m0 + l15) * TSP + quad * 8];
      const u16* wb = w2b + (p & 1) * 4096;
      #pragma unroll
      for (int nt = 0; nt < 8; ++nt) {
        bf16x8 bfr = *(const bf16x8*)&wb[nt * 512 + lane * 8];
        acc2[nt] = __builtin_amdgcn_mfma_f32_16x16x32_bf16(tf, bfr, acc2[nt], 0, 0, 0);
      }
      if (s2) {
        uint4* d = (uint4*)(w2b + ((p + 1) & 1) * 4096);
        d[tid] = s0; d[tid + 256] = s1;
      }
      if (s1n) {
        ((uint4*)w1b)[tid] = s0; ((uint4*)w1b)[tid + 256] = s1;
        ((uint4*)w2b)[tid] = t0; ((uint4*)w2b)[tid + 256] = t1;
      }
      __syncthreads();
    }
  }
  #pragma unroll
  for (int nt = 0; nt < 8; ++nt) {
    int col = nt * 16 + l15;
    float bb = b2[col];
    #pragma unroll
    for (int r = 0; r < 4; ++r) {
      size_t idx = (row0 + m0 + quad * 4 + r) * Dx + col;
      if (abp) x[idx] = acc2[nt][r] + bb;    // acc2 already carries x_new
      else     x[idx] += acc2[nt][r] + bb;
    }
  }
}

// ---------------- final FC (MFMA, split-K 32) ----------------
__global__ __launch_bounds__(256, 4)
void k_fc(const float* __restrict__ x, const u16* __restrict__ fcWs,
          float* __restrict__ part) {
  const int tid = threadIdx.x;
  const int lane = tid & 63, wv = tid >> 6;
  const int l15 = lane & 15, quad = lane >> 4;
  const int m0 = blockIdx.x * 64 + wv * 16;
  const int ky = blockIdx.y;
  f32x4 acc[8];
  #pragma unroll
  for (int i = 0; i < 8; ++i) acc[i] = (f32x4){0.f, 0.f, 0.f, 0.f};
  const float* xp = x + (size_t)(m0 + l15) * 25600 + quad * 8;
  #pragma unroll 1
  for (int kst = ky * 25; kst < ky * 25 + 25; ++kst) {
    float4 xa = *(const float4*)(xp + kst * 32);
    float4 xb2 = *(const float4*)(xp + kst * 32 + 4);
    bf16x8 af;
    af[0] = (short)f2bf(xa.x);  af[1] = (short)f2bf(xa.y);
    af[2] = (short)f2bf(xa.z);  af[3] = (short)f2bf(xa.w);
    af[4] = (short)f2bf(xb2.x); af[5] = (short)f2bf(xb2.y);
    af[6] = (short)f2bf(xb2.z); af[7] = (short)f2bf(xb2.w);
    const u16* wb = fcWs + ((size_t)kst * 64 + lane) * 8;
    #pragma unroll
    for (int nt = 0; nt < 8; ++nt) {
      bf16x8 bf = *(const bf16x8*)(wb + (size_t)nt * (800 * 64 * 8));
      acc[nt] = __builtin_amdgcn_mfma_f32_16x16x32_bf16(af, bf, acc[nt], 0, 0, 0);
    }
  }
  float* pp = part + (size_t)ky * (Bx * Dx);
  #pragma unroll
  for (int nt = 0; nt < 8; ++nt) {
    #pragma unroll
    for (int r = 0; r < 4; ++r) {
      pp[(size_t)(m0 + quad * 4 + r) * Dx + nt * 16 + l15] = acc[nt][r];
    }
  }
}

__global__ void k_fcred(const float* __restrict__ part, const float* __restrict__ fcb,
                        float* __restrict__ out) {
  int i = blockIdx.x * 256 + threadIdx.x;
  float s = fcb[i & 127];
  #pragma unroll
  for (int k = 0; k < 32; ++k) s += part[(size_t)k * (Bx * Dx) + i];
  out[i] = s;
}

extern "C" void kernel_launch(void* const* d_in, const int* in_sizes, int n_in,
                              void* d_out, int out_size, void* d_ws, size_t ws_size,
                              hipStream_t stream) {
  const int*   seq  = (const int*)d_in[0];
  const float* tok  = (const float*)d_in[1];
  const float* pos  = (const float*)d_in[2];
  const float* Wq   = (const float*)d_in[3];
  const float* bq   = (const float*)d_in[4];
  const float* Wk   = (const float*)d_in[5];
  const float* bk   = (const float*)d_in[6];
  const float* Wv   = (const float*)d_in[7];
  const float* bv   = (const float*)d_in[8];
  const float* Wo   = (const float*)d_in[9];
  const float* bo   = (const float*)d_in[10];
  const float* ln1w = (const float*)d_in[11];
  const float* ln1b = (const float*)d_in[12];
  const float* ln2w = (const float*)d_in[13];
  const float* ln2b = (const float*)d_in[14];
  const float* W1   = (const float*)d_in[15];
  const float* b1   = (const float*)d_in[16];
  const float* W2   = (const float*)d_in[17];
  const float* b2   = (const float*)d_in[18];
  const float* fcW  = (const float*)d_in[19];
  const float* fcb  = (const float*)d_in[20];
  float* out = (float*)d_out;

  char* ws = (char*)d_ws;
  const size_t XB  = (size_t)Mx * Dx * 4;        // 104,857,600 B
  const size_t ABF = (size_t)Mx * Dx * 2;        // 52,428,800 B (full attn-out)
  const size_t WBSZ = 7340032;                   // converted-weight region

  // Preferred layout: x | q,k,v (chunked) | ab (FULL) | weights  -> oproj fused
  // into k_ffn. Fallback (tight ws): old layout with chunked ab + k_oproj.
  int nc = 0;
  for (int t = 1; t <= 32; t <<= 1) {
    size_t q3 = 3 * ((size_t)(Bx / t) * 51200);
    if (XB + q3 + ABF + WBSZ <= ws_size) { nc = t; break; }
  }
  const bool fused = (nc != 0);
  if (!fused) nc = 4;
  const int BC = Bx / nc;
  const size_t qsz = (size_t)BC * 51200;

  float* x    = (float*)ws;
  u16* qb     = (u16*)(ws + XB);
  u16* kb     = (u16*)(ws + XB + qsz);
  u16* vb     = (u16*)(ws + XB + 2 * qsz);
  u16* ab     = (u16*)(ws + XB + 3 * qsz);       // full-size if fused, chunk if not
  float* part = (float*)(ws + XB);               // aliases q/k/v/ab (dead by k_fc)
  char* WB    = fused ? (ws + XB + 3 * qsz + ABF) : (ws + XB + 4 * qsz);
  u16* W1s0   = (u16*)(WB);
  u16* W1s1   = (u16*)(WB + 131072);
  u16* W2s0   = (u16*)(WB + 262144);
  u16* W2s1   = (u16*)(WB + 393216);
  u16* Wos0   = (u16*)(WB + 524288);
  u16* Wos1   = (u16*)(WB + 557056);
  u16* Wqkvs0 = (u16*)(WB + 589824);
  u16* Wqkvs1 = (u16*)(WB + 688128);
  u16* fcWs   = (u16*)(WB + 786432);

  // ---- merged weight conversion: ONE launch for all 13 tensors ----
  CvtJobs J;
  const float* srcs[13] = {W1, W1 + Dx * FFx, W2, W2 + FFx * Dx,
                           Wo, Wo + Dx * Dx,
                           Wq, Wk, Wv,
                           Wq + Dx * Dx, Wk + Dx * Dx, Wv + Dx * Dx,
                           fcW};
  u16* dsts[13] = {W1s0, W1s1, W2s0, W2s1, Wos0, Wos1,
                   Wqkvs0, Wqkvs0 + 16384, Wqkvs0 + 32768,
                   Wqkvs1, Wqkvs1 + 16384, Wqkvs1 + 32768,
                   fcWs};
  const int Ns[13]  = {FFx, FFx, Dx, Dx, Dx, Dx, Dx, Dx, Dx, Dx, Dx, Dx, Dx};
  const int kss[13] = {4, 4, 16, 16, 4, 4, 4, 4, 4, 4, 4, 4, 800};
  const int nblk[13] = {32, 32, 32, 32, 8, 8, 8, 8, 8, 8, 8, 8, 1600};
  int acc = 0;
  for (int j = 0; j < 13; ++j) {
    J.src[j] = srcs[j]; J.dst[j] = dsts[j]; J.N[j] = Ns[j]; J.ks[j] = kss[j];
    J.bstart[j] = acc; acc += nblk[j];
  }
  J.bstart[13] = acc;   // 1792
  k_cvt_all<<<acc, 256, 0, stream>>>(J);

  k_embed<<<25600, 256, 0, stream>>>(seq, tok, pos, x);
  const int cblk = BC * 200 / 64;   // 64-row blocks per chunk
  for (int i = 0; i < 2; ++i) {
    const u16* Wqkvs = (i == 0) ? Wqkvs0 : Wqkvs1;
    const u16* Wos   = (i == 0) ? Wos0 : Wos1;
    for (int c = 0; c < nc; ++c) {
      float* xc = x + (size_t)c * BC * 200 * 128;
      const int* seqc = seq + (size_t)c * BC * 200;
      k_qkv<<<cblk, 256, 0, stream>>>(xc, ln1w + i * Dx, ln1b + i * Dx, Wqkvs,
                                      bq + i * Dx, bk + i * Dx, bv + i * Dx,
                                      qb, kb, vb);
      u16* abc = fused ? ab + (size_t)c * BC * 200 * 128 : ab;
      k_attn2<<<BC * 4, 256, 0, stream>>>(qb, kb, vb, seqc, abc);
      if (!fused)
        k_oproj<<<cblk, 256, 0, stream>>>(ab, Wos, bo + i * Dx, xc);
    }
    k_ffn<<<3200, 256, 0, stream>>>(x, fused ? ab : nullptr, Wos, bo + i * Dx,
                                    ln2w + i * Dx, ln2b + i * Dx,
                                    (i == 0) ? W1s0 : W1s1, b1 + i * FFx,
                                    (i == 0) ? W2s0 : W2s1, b2 + i * Dx);
  }
  k_fc<<<dim3(16, 32), 256, 0, stream>>>(x, fcWs, part);
  k_fcred<<<512, 256, 0, stream>>>(part, fcb, out);
}

// Round 13
// 996.953 us; speedup vs baseline: 1.0362x; 1.0362x over previous
//
#include <hip/hip_runtime.h>
#include <math.h>

typedef unsigned short u16;
typedef unsigned int u32;
typedef __attribute__((ext_vector_type(8))) short bf16x8;
typedef __attribute__((ext_vector_type(4))) float f32x4;

#define Bx 1024
#define Lx 200
#define Dx 128
#define FFx 512
#define Mx (Bx*Lx)
#define PVP 232   // P/V^T LDS row stride (u16)
#define LNP 136   // hs row stride (u16): used for LN-transpose + gelu slices

__device__ __forceinline__ u16 f2bf(float f) {
  u32 u = __float_as_uint(f);
  u32 r = (u + 0x7fffu + ((u >> 16) & 1u)) >> 16;
  return (u16)r;
}

// fast GELU: tanh form, v*sigmoid(1.59577v + 0.0713548 v^3).
// |err| vs exact erf-gelu < 1e-4 for |v|<2 (pre-act sigma~0.23) — below bf16 eps.
__device__ __forceinline__ float gelu_f(float v) {
  float z = v * fmaf(v * v, 0.0713548163f, 1.5957691216f);
  float e = __expf(-z);
  return v * __builtin_amdgcn_rcpf(1.0f + e);
}

union BFCV { u32 u[4]; bf16x8 h; };

// ---------------- merged weight convert: fp32 [K][N] -> bf16 fragment order -------
struct CvtJobs {
  const float* src[13];
  u16* dst[13];
  int N[13];
  int ks[13];
  int bstart[14];
};

__global__ void k_cvt_all(CvtJobs J) {
  const int b = blockIdx.x;
  int j = 0;
  #pragma unroll 1
  while (b >= J.bstart[j + 1]) ++j;          // uniform per block (scalar)
  const float* __restrict__ src = J.src[j];
  u16* __restrict__ dst = J.dst[j];
  const int N = J.N[j], k_steps = J.ks[j];
  int id = (b - J.bstart[j]) * 256 + threadIdx.x;
  int lane = id & 63;
  int rest = id >> 6;
  int kst = rest % k_steps;
  int ntile = rest / k_steps;
  int n = ntile * 16 + (lane & 15);
  int kb = kst * 32 + ((lane >> 4) << 3);
  const float* sp = src + (size_t)kb * N + n;
  u32 w[4];
  #pragma unroll
  for (int jj = 0; jj < 4; ++jj) {
    u32 lo = f2bf(sp[(size_t)(2 * jj) * N]);
    u32 hi = f2bf(sp[(size_t)(2 * jj + 1) * N]);
    w[jj] = lo | (hi << 16);
  }
  ((uint4*)dst)[id] = make_uint4(w[0], w[1], w[2], w[3]);
}

// ---------------- embedding: x = tok[seq] + pos ----------------
__global__ void k_embed(const int* __restrict__ seq, const float* __restrict__ tok,
                        const float* __restrict__ pos, float* __restrict__ x) {
  const int i = blockIdx.x * 256 + threadIdx.x;
  const int row = i >> 5, c = i & 31;
  const int t = seq[row];
  const int l = row % Lx;
  const float4 a = ((const float4*)tok)[(size_t)t * 32 + c];
  const float4 p = ((const float4*)pos)[l * 32 + c];
  ((float4*)x)[i] = make_float4(a.x + p.x, a.y + p.y, a.z + p.z, a.w + p.w);
}

// ---- register layernorm: lane (quad,l15) owns one row; row stats reduced across
// the 4 quad-lanes via shfl_xor(16/32). Packs af[] A-frags.
__device__ __forceinline__ void reg_ln(const float* __restrict__ xr,
                                       const float* __restrict__ ln_w,
                                       const float* __restrict__ ln_b,
                                       int quad, bf16x8 af[4]) {
  float v[32];
  float s = 0.f, sq = 0.f;
  #pragma unroll
  for (int kst = 0; kst < 4; ++kst) {
    float4 a = *(const float4*)(xr + kst * 32);
    float4 b = *(const float4*)(xr + kst * 32 + 4);
    v[kst * 8 + 0] = a.x; v[kst * 8 + 1] = a.y; v[kst * 8 + 2] = a.z; v[kst * 8 + 3] = a.w;
    v[kst * 8 + 4] = b.x; v[kst * 8 + 5] = b.y; v[kst * 8 + 6] = b.z; v[kst * 8 + 7] = b.w;
  }
  #pragma unroll
  for (int i = 0; i < 32; ++i) { s += v[i]; sq = fmaf(v[i], v[i], sq); }
  s  += __shfl_xor(s, 16);  s  += __shfl_xor(s, 32);
  sq += __shfl_xor(sq, 16); sq += __shfl_xor(sq, 32);
  float mu = s * 0.0078125f;
  float rr = rsqrtf(fmaf(-mu, mu, sq * 0.0078125f) + 1e-5f);
  #pragma unroll
  for (int kst = 0; kst < 4; ++kst) {
    const float* lwp = ln_w + kst * 32 + quad * 8;
    const float* lbp = ln_b + kst * 32 + quad * 8;
    float4 lw0 = *(const float4*)(lwp);
    float4 lw1 = *(const float4*)(lwp + 4);
    float4 lb0 = *(const float4*)(lbp);
    float4 lb1 = *(const float4*)(lbp + 4);
    float hw[8] = {lw0.x, lw0.y, lw0.z, lw0.w, lw1.x, lw1.y, lw1.z, lw1.w};
    float hb[8] = {lb0.x, lb0.y, lb0.z, lb0.w, lb1.x, lb1.y, lb1.z, lb1.w};
    BFCV cv;
    #pragma unroll
    for (int j = 0; j < 4; ++j) {
      float h0 = fmaf((v[kst * 8 + 2 * j]     - mu) * rr, hw[2 * j],     hb[2 * j]);
      float h1 = fmaf((v[kst * 8 + 2 * j + 1] - mu) * rr, hw[2 * j + 1], hb[2 * j + 1]);
      cv.u[j] = (u32)f2bf(h0) | ((u32)f2bf(h1) << 16);
    }
    af[kst] = cv.h;
  }
}

// ---------------- fused LN + QKV GEMM (MFMA), register LN, no LDS ----------------
__global__ __launch_bounds__(256, 4)
void k_qkv(const float* __restrict__ x, const float* __restrict__ ln_w,
           const float* __restrict__ ln_b, const u16* __restrict__ Wqkvs,
           const float* __restrict__ bq, const float* __restrict__ bk,
           const float* __restrict__ bv,
           u16* __restrict__ qo, u16* __restrict__ ko, u16* __restrict__ vo) {
  const int tid = threadIdx.x;
  const int row0 = blockIdx.x * 64;
  const int lane = tid & 63, wv = tid >> 6;
  const int l15 = lane & 15, quad = lane >> 4;
  const int m0 = wv * 16;

  bf16x8 af[4];
  reg_ln(x + (size_t)(row0 + m0 + l15) * Dx + quad * 8, ln_w, ln_b, quad, af);

  int bl[4], ll[4];
  #pragma unroll
  for (int r = 0; r < 4; ++r) {
    int gr = row0 + m0 + quad * 4 + r;
    bl[r] = gr / 200;
    ll[r] = gr - bl[r] * 200;
  }

  const float scale = 0.17677669529663687f;
  #pragma unroll
  for (int nt = 0; nt < 24; ++nt) {
    f32x4 acc = (f32x4){0.f, 0.f, 0.f, 0.f};
    const u16* wb = Wqkvs + ((size_t)(nt * 4) * 64 + lane) * 8;
    #pragma unroll
    for (int kst = 0; kst < 4; ++kst) {
      bf16x8 bfr = *(const bf16x8*)(wb + kst * 64 * 8);
      acc = __builtin_amdgcn_mfma_f32_16x16x32_bf16(af[kst], bfr, acc, 0, 0, 0);
    }
    const int col = (nt & 7) * 16 + l15;
    const int head = col >> 5, dk = col & 31;
    if (nt < 8) {
      float bb = bq[col];
      #pragma unroll
      for (int r = 0; r < 4; ++r)
        qo[((size_t)(bl[r] * 4 + head) * 200 + ll[r]) * 32 + dk] = f2bf((acc[r] + bb) * scale);
    } else if (nt < 16) {
      float bb = bk[col];
      #pragma unroll
      for (int r = 0; r < 4; ++r)
        ko[((size_t)(bl[r] * 4 + head) * 200 + ll[r]) * 32 + dk] = f2bf(acc[r] + bb);
    } else {
      float bb = bv[col];
      #pragma unroll
      for (int r = 0; r < 4; ++r)
        vo[((size_t)(bl[r] * 4 + head) * 200 + ll[r]) * 32 + dk] = f2bf(acc[r] + bb);
    }
  }
}

// ---------------- MFMA attention: one block per (b_local, head) ----------------
__global__ __launch_bounds__(256, 3)
void k_attn2(const u16* __restrict__ q, const u16* __restrict__ k,
             const u16* __restrict__ v, const int* __restrict__ seq,
             u16* __restrict__ attn) {
  __shared__ float smask[224];
  __shared__ __align__(16) u16 vt[32 * PVP];
  __shared__ __align__(16) u16 Pb[4][16 * PVP];
  const int tid = threadIdx.x;
  const int bl = blockIdx.x >> 2, head = blockIdx.x & 3;
  const int bh = blockIdx.x;
  const int lane = tid & 63, wv = tid >> 6;
  const int l15 = lane & 15, quad = lane >> 4;

  if (tid < 224)
    smask[tid] = (tid < 200 && seq[bl * 200 + tid] > 0) ? 0.f : -1e9f;
  // stage V^T into LDS: vt[dk][l]
  #pragma unroll 1
  for (int e = tid; e < 800; e += 256) {
    int l = e >> 2, g = (e & 3) * 8;
    uint4 pv = *(const uint4*)(v + ((size_t)bh * 200 + l) * 32 + g);
    const u16* pw = (const u16*)&pv;
    #pragma unroll
    for (int j = 0; j < 8; ++j) vt[(g + j) * PVP + l] = pw[j];
  }
  // zero V^T pad cols [200,232)
  #pragma unroll 1
  for (int e = tid; e < 1024; e += 256) {
    int rr = e >> 5, cc = 200 + (e & 31);
    vt[rr * PVP + cc] = 0;
  }
  __syncthreads();

  float msk[14];
  #pragma unroll
  for (int nt = 0; nt < 14; ++nt) msk[nt] = smask[nt * 16 + l15];

  const u16* qbase = q + (size_t)bh * 200 * 32;
  const u16* kbase = k + (size_t)bh * 200 * 32;
  u16* Pw = Pb[wv];

  #pragma unroll 1
  for (int mt = wv; mt < 13; mt += 4) {
    bf16x8 qf = *(const bf16x8*)(qbase + (mt * 16 + l15) * 32 + quad * 8);
    f32x4 s[14];
    #pragma unroll
    for (int nt = 0; nt < 14; ++nt) {
      bf16x8 kf = *(const bf16x8*)(kbase + (nt * 16 + l15) * 32 + quad * 8);
      s[nt] = __builtin_amdgcn_mfma_f32_16x16x32_bf16(qf, kf, (f32x4){0.f, 0.f, 0.f, 0.f}, 0, 0, 0);
    }
    // mask + row max
    float rmax[4] = {-1e30f, -1e30f, -1e30f, -1e30f};
    #pragma unroll
    for (int nt = 0; nt < 14; ++nt) {
      #pragma unroll
      for (int r = 0; r < 4; ++r) {
        s[nt][r] += msk[nt];
        rmax[r] = fmaxf(rmax[r], s[nt][r]);
      }
    }
    #pragma unroll
    for (int m = 1; m < 16; m <<= 1) {
      #pragma unroll
      for (int r = 0; r < 4; ++r) rmax[r] = fmaxf(rmax[r], __shfl_xor(rmax[r], m));
    }
    // exp + row sum
    float rsum[4] = {0.f, 0.f, 0.f, 0.f};
    #pragma unroll
    for (int nt = 0; nt < 14; ++nt) {
      #pragma unroll
      for (int r = 0; r < 4; ++r) {
        float p = __expf(s[nt][r] - rmax[r]);
        s[nt][r] = p;
        rsum[r] += p;
      }
    }
    #pragma unroll
    for (int m = 1; m < 16; m <<= 1) {
      #pragma unroll
      for (int r = 0; r < 4; ++r) rsum[r] += __shfl_xor(rsum[r], m);
    }
    float inv[4];
    #pragma unroll
    for (int r = 0; r < 4; ++r) inv[r] = 1.0f / rsum[r];
    // P -> wave-private LDS (bf16, unnormalized)
    #pragma unroll
    for (int nt = 0; nt < 14; ++nt) {
      #pragma unroll
      for (int r = 0; r < 4; ++r)
        Pw[(quad * 4 + r) * PVP + nt * 16 + l15] = f2bf(s[nt][r]);
    }
    __asm__ __volatile__("s_waitcnt lgkmcnt(0)" ::: "memory");
    // O = P @ V
    f32x4 o0 = (f32x4){0.f, 0.f, 0.f, 0.f}, o1 = (f32x4){0.f, 0.f, 0.f, 0.f};
    #pragma unroll
    for (int kst = 0; kst < 7; ++kst) {
      bf16x8 pf  = *(const bf16x8*)&Pw[l15 * PVP + kst * 32 + quad * 8];
      bf16x8 vf0 = *(const bf16x8*)&vt[l15 * PVP + kst * 32 + quad * 8];
      bf16x8 vf1 = *(const bf16x8*)&vt[(16 + l15) * PVP + kst * 32 + quad * 8];
      o0 = __builtin_amdgcn_mfma_f32_16x16x32_bf16(pf, vf0, o0, 0, 0, 0);
      o1 = __builtin_amdgcn_mfma_f32_16x16x32_bf16(pf, vf1, o1, 0, 0, 0);
    }
    #pragma unroll
    for (int r = 0; r < 4; ++r) {
      int row = mt * 16 + quad * 4 + r;
      if (row < 200) {
        u16* op = attn + ((size_t)bl * 200 + row) * 128 + head * 32;
        op[l15]      = f2bf(o0[r] * inv[r]);
        op[16 + l15] = f2bf(o1[r] * inv[r]);
      }
    }
  }
}

// ---------------- O-projection + residual (MFMA): x += a @ Wo + bo ----------------
// (fallback path only — used when workspace can't hold a full-size ab buffer)
__global__ __launch_bounds__(256, 4)
void k_oproj(const u16* __restrict__ a, const u16* __restrict__ Wos,
             const float* __restrict__ bo, float* __restrict__ x) {
  const int tid = threadIdx.x;
  const int lane = tid & 63, wv = tid >> 6;
  const int l15 = lane & 15, quad = lane >> 4;
  const size_t m0 = (size_t)blockIdx.x * 64 + wv * 16;
  f32x4 acc[8];
  #pragma unroll
  for (int i = 0; i < 8; ++i) acc[i] = (f32x4){0.f, 0.f, 0.f, 0.f};
  #pragma unroll
  for (int kst = 0; kst < 4; ++kst) {
    bf16x8 af = *(const bf16x8*)(a + (m0 + l15) * Dx + kst * 32 + quad * 8);
    const u16* wb = Wos + (kst * 64 + lane) * 8;
    #pragma unroll
    for (int nt = 0; nt < 8; ++nt) {
      bf16x8 bf = *(const bf16x8*)(wb + nt * (4 * 64 * 8));
      acc[nt] = __builtin_amdgcn_mfma_f32_16x16x32_bf16(af, bf, acc[nt], 0, 0, 0);
    }
  }
  #pragma unroll
  for (int nt = 0; nt < 8; ++nt) {
    int col = nt * 16 + l15;
    float bb = bo[col];
    #pragma unroll
    for (int r = 0; r < 4; ++r) {
      size_t idx = (m0 + quad * 4 + r) * Dx + col;
      x[idx] += acc[nt][r] + bb;
    }
  }
}

// ------- fused [oproj + residual + LN] + FFN (MFMA) -------
// Fused path (abp != nullptr): phase 0 computes x_new = x + ab@Wo + bo INTO acc2
// (the W2-GEMM C-operand — rides through accumulation; epilogue is a plain store).
// x_new is NEVER written to global pre-epilogue (r12's global round-trip caused
// +200 MB HBM writes and a serial stall). LN is computed from acc2 registers:
// row stats via Σ_nt + shfl_xor(1,2,4,8) across the 16 l15-lanes of each quad;
// normalized bf16 h transposed C-layout -> A-layout through wave-private hs rows.
__global__ __launch_bounds__(256, 4)
void k_ffn(float* __restrict__ x, const u16* __restrict__ abp,
           const u16* __restrict__ Wos, const float* __restrict__ bo,
           const float* __restrict__ ln_w, const float* __restrict__ ln_b,
           const u16* __restrict__ W1s, const float* __restrict__ b1,
           const u16* __restrict__ W2s, const float* __restrict__ b2) {
  __shared__ __align__(16) u16 smem[64 * LNP + 8192 + 8192];
  u16* hs  = smem;                 // [64][LNP] — LN transpose + gelu slices
  u16* w1b = smem + 64 * LNP;      // 2 x 4096 u16 (8 KB each)
  u16* w2b = w1b + 8192;           // 2 x 4096 u16
  const int tid = threadIdx.x;
  const size_t row0 = (size_t)blockIdx.x * 64;
  const int lane = tid & 63, wv = tid >> 6;           // wv in [0,4)
  const int l15 = lane & 15, quad = lane >> 4;
  const int m0 = wv * 16;
  const int nt0 = tid >> 6, off = tid & 63;           // staging: 2 x 1KB pieces/thread

  f32x4 acc2[8];
  #pragma unroll
  for (int i = 0; i < 8; ++i) acc2[i] = (f32x4){0.f, 0.f, 0.f, 0.f};
  bf16x8 af[4];

  if (abp) {
    // ---- phase 0: oproj -> acc2 ----
    #pragma unroll
    for (int kst = 0; kst < 4; ++kst) {
      bf16x8 abf = *(const bf16x8*)(abp + (row0 + m0 + l15) * (size_t)Dx + kst * 32 + quad * 8);
      const u16* wb = Wos + (kst * 64 + lane) * 8;
      #pragma unroll
      for (int nt = 0; nt < 8; ++nt) {
        bf16x8 wf = *(const bf16x8*)(wb + nt * (4 * 64 * 8));
        acc2[nt] = __builtin_amdgcn_mfma_f32_16x16x32_bf16(abf, wf, acc2[nt], 0, 0, 0);
      }
    }
    // residual: acc2 += x_old + bo  (x_new now lives ONLY in acc2)
    #pragma unroll
    for (int nt = 0; nt < 8; ++nt) {
      int col = nt * 16 + l15;
      float bb = bo[col];
      #pragma unroll
      for (int r = 0; r < 4; ++r)
        acc2[nt][r] += x[(row0 + m0 + quad * 4 + r) * (size_t)Dx + col] + bb;
    }
    // in-register LN stats over acc2: rows m0+quad*4+r, cols nt*16+l15
    float s[4] = {0.f, 0.f, 0.f, 0.f}, sq[4] = {0.f, 0.f, 0.f, 0.f};
    #pragma unroll
    for (int nt = 0; nt < 8; ++nt)
      #pragma unroll
      for (int r = 0; r < 4; ++r) {
        float v = acc2[nt][r];
        s[r] += v;
        sq[r] = fmaf(v, v, sq[r]);
      }
    #pragma unroll
    for (int m = 1; m < 16; m <<= 1) {
      #pragma unroll
      for (int r = 0; r < 4; ++r) {
        s[r]  += __shfl_xor(s[r], m);
        sq[r] += __shfl_xor(sq[r], m);
      }
    }
    float mu[4], rr[4];
    #pragma unroll
    for (int r = 0; r < 4; ++r) {
      mu[r] = s[r] * 0.0078125f;
      rr[r] = rsqrtf(fmaf(-mu[r], mu[r], sq[r] * 0.0078125f) + 1e-5f);
    }
    // h -> hs (C-layout, wave-private rows)
    #pragma unroll
    for (int nt = 0; nt < 8; ++nt) {
      int col = nt * 16 + l15;
      float lw = ln_w[col], lb = ln_b[col];
      #pragma unroll
      for (int r = 0; r < 4; ++r)
        hs[(m0 + quad * 4 + r) * LNP + col] =
            f2bf(fmaf((acc2[nt][r] - mu[r]) * rr[r], lw, lb));
    }
  } else {
    reg_ln(x + (row0 + m0 + l15) * (size_t)Dx + quad * 8, ln_w, ln_b, quad, af);
  }

  // prologue: stage W1(ch0,kst0) and W2(ch0,p0) — 8 KB each, 2 uint4/thread
  ((uint4*)w1b)[tid]       = ((const uint4*)(W1s + (size_t)(nt0 * 4) * 512))[off];
  ((uint4*)w1b)[tid + 256] = ((const uint4*)(W1s + (size_t)((nt0 + 4) * 4) * 512))[off];
  ((uint4*)w2b)[tid]       = ((const uint4*)(W2s + (size_t)(nt0 * 16) * 512))[off];
  ((uint4*)w2b)[tid + 256] = ((const uint4*)(W2s + (size_t)((nt0 + 4) * 16) * 512))[off];
  __syncthreads();   // drains staging + hs writes

  if (abp) {
    // A-fragments from hs (A-layout read, wave-private rows)
    #pragma unroll
    for (int kst = 0; kst < 4; ++kst)
      af[kst] = *(const bf16x8*)&hs[(m0 + l15) * LNP + kst * 32 + quad * 8];
  }

  #pragma unroll 1
  for (int ch = 0; ch < 4; ++ch) {
    // ---- GEMM1: 4 kst phases, dbuf, async-split staging ----
    f32x4 acc1[8];
    #pragma unroll
    for (int i = 0; i < 8; ++i) acc1[i] = (f32x4){0.f, 0.f, 0.f, 0.f};
    #pragma unroll
    for (int kst = 0; kst < 4; ++kst) {
      uint4 s0, s1;
      if (kst < 3) {
        s0 = ((const uint4*)(W1s + (size_t)((ch * 8 + nt0) * 4 + kst + 1) * 512))[off];
        s1 = ((const uint4*)(W1s + (size_t)((ch * 8 + nt0 + 4) * 4 + kst + 1) * 512))[off];
      }
      const u16* wb = w1b + (kst & 1) * 4096;
      #pragma unroll
      for (int nt = 0; nt < 8; ++nt) {
        bf16x8 bfr = *(const bf16x8*)&wb[nt * 512 + lane * 8];
        acc1[nt] = __builtin_amdgcn_mfma_f32_16x16x32_bf16(af[kst], bfr, acc1[nt], 0, 0, 0);
      }
      if (kst < 3) {
        uint4* d = (uint4*)(w1b + ((kst + 1) & 1) * 4096);
        d[tid] = s0; d[tid + 256] = s1;
      }
      __syncthreads();
    }
    // ---- GELU + GEMM2: 4 p phases; gelu slice p feeds kst p ----
    #pragma unroll
    for (int p = 0; p < 4; ++p) {
      uint4 s0, s1, t0, t1;
      const bool s2  = (p < 3);
      const bool s1n = (p == 3) && (ch < 3);
      if (s2) {
        s0 = ((const uint4*)(W2s + (size_t)(nt0 * 16 + ch * 4 + p + 1) * 512))[off];
        s1 = ((const uint4*)(W2s + (size_t)((nt0 + 4) * 16 + ch * 4 + p + 1) * 512))[off];
      }
      if (s1n) {
        s0 = ((const uint4*)(W1s + (size_t)(((ch + 1) * 8 + nt0) * 4) * 512))[off];
        s1 = ((const uint4*)(W1s + (size_t)(((ch + 1) * 8 + nt0 + 4) * 4) * 512))[off];
        t0 = ((const uint4*)(W2s + (size_t)(nt0 * 16 + (ch + 1) * 4) * 512))[off];
        t1 = ((const uint4*)(W2s + (size_t)((nt0 + 4) * 16 + (ch + 1) * 4) * 512))[off];
      }
      // GELU slice p (cols p*32..p*32+32 of this ch) -> hs cols [0,32), wave rows
      #pragma unroll
      for (int q2 = 0; q2 < 2; ++q2) {
        const int ntg = 2 * p + q2;
        float bb = b1[ch * 128 + ntg * 16 + l15];
        #pragma unroll
        for (int r = 0; r < 4; ++r)
          hs[(m0 + quad * 4 + r) * LNP + q2 * 16 + l15] =
              f2bf(gelu_f(acc1[ntg][r] + bb));
      }
      __asm__ __volatile__("s_waitcnt lgkmcnt(0)" ::: "memory");
      bf16x8 tf = *(const bf16x8*)&hs[(m0 + l15) * LNP + quad * 8];
      const u16* wb = w2b + (p & 1) * 4096;
      #pragma unroll
      for (int nt = 0; nt < 8; ++nt) {
        bf16x8 bfr = *(const bf16x8*)&wb[nt * 512 + lane * 8];
        acc2[nt] = __builtin_amdgcn_mfma_f32_16x16x32_bf16(tf, bfr, acc2[nt], 0, 0, 0);
      }
      if (s2) {
        uint4* d = (uint4*)(w2b + ((p + 1) & 1) * 4096);
        d[tid] = s0; d[tid + 256] = s1;
      }
      if (s1n) {
        ((uint4*)w1b)[tid] = s0; ((uint4*)w1b)[tid + 256] = s1;
        ((uint4*)w2b)[tid] = t0; ((uint4*)w2b)[tid + 256] = t1;
      }
      __syncthreads();
    }
  }
  #pragma unroll
  for (int nt = 0; nt < 8; ++nt) {
    int col = nt * 16 + l15;
    float bb = b2[col];
    #pragma unroll
    for (int r = 0; r < 4; ++r) {
      size_t idx = (row0 + m0 + quad * 4 + r) * Dx + col;
      if (abp) x[idx] = acc2[nt][r] + bb;    // acc2 carries x_new
      else     x[idx] += acc2[nt][r] + bb;
    }
  }
}

// ---------------- final FC (MFMA, split-K 32) ----------------
__global__ __launch_bounds__(256, 4)
void k_fc(const float* __restrict__ x, const u16* __restrict__ fcWs,
          float* __restrict__ part) {
  const int tid = threadIdx.x;
  const int lane = tid & 63, wv = tid >> 6;
  const int l15 = lane & 15, quad = lane >> 4;
  const int m0 = blockIdx.x * 64 + wv * 16;
  const int ky = blockIdx.y;
  f32x4 acc[8];
  #pragma unroll
  for (int i = 0; i < 8; ++i) acc[i] = (f32x4){0.f, 0.f, 0.f, 0.f};
  const float* xp = x + (size_t)(m0 + l15) * 25600 + quad * 8;
  #pragma unroll 1
  for (int kst = ky * 25; kst < ky * 25 + 25; ++kst) {
    float4 xa = *(const float4*)(xp + kst * 32);
    float4 xb2 = *(const float4*)(xp + kst * 32 + 4);
    bf16x8 af;
    af[0] = (short)f2bf(xa.x);  af[1] = (short)f2bf(xa.y);
    af[2] = (short)f2bf(xa.z);  af[3] = (short)f2bf(xa.w);
    af[4] = (short)f2bf(xb2.x); af[5] = (short)f2bf(xb2.y);
    af[6] = (short)f2bf(xb2.z); af[7] = (short)f2bf(xb2.w);
    const u16* wb = fcWs + ((size_t)kst * 64 + lane) * 8;
    #pragma unroll
    for (int nt = 0; nt < 8; ++nt) {
      bf16x8 bf = *(const bf16x8*)(wb + (size_t)nt * (800 * 64 * 8));
      acc[nt] = __builtin_amdgcn_mfma_f32_16x16x32_bf16(af, bf, acc[nt], 0, 0, 0);
    }
  }
  float* pp = part + (size_t)ky * (Bx * Dx);
  #pragma unroll
  for (int nt = 0; nt < 8; ++nt) {
    #pragma unroll
    for (int r = 0; r < 4; ++r) {
      pp[(size_t)(m0 + quad * 4 + r) * Dx + nt * 16 + l15] = acc[nt][r];
    }
  }
}

__global__ void k_fcred(const float* __restrict__ part, const float* __restrict__ fcb,
                        float* __restrict__ out) {
  int i = blockIdx.x * 256 + threadIdx.x;
  float s = fcb[i & 127];
  #pragma unroll
  for (int k = 0; k < 32; ++k) s += part[(size_t)k * (Bx * Dx) + i];
  out[i] = s;
}

extern "C" void kernel_launch(void* const* d_in, const int* in_sizes, int n_in,
                              void* d_out, int out_size, void* d_ws, size_t ws_size,
                              hipStream_t stream) {
  const int*   seq  = (const int*)d_in[0];
  const float* tok  = (const float*)d_in[1];
  const float* pos  = (const float*)d_in[2];
  const float* Wq   = (const float*)d_in[3];
  const float* bq   = (const float*)d_in[4];
  const float* Wk   = (const float*)d_in[5];
  const float* bk   = (const float*)d_in[6];
  const float* Wv   = (const float*)d_in[7];
  const float* bv   = (const float*)d_in[8];
  const float* Wo   = (const float*)d_in[9];
  const float* bo   = (const float*)d_in[10];
  const float* ln1w = (const float*)d_in[11];
  const float* ln1b = (const float*)d_in[12];
  const float* ln2w = (const float*)d_in[13];
  const float* ln2b = (const float*)d_in[14];
  const float* W1   = (const float*)d_in[15];
  const float* b1   = (const float*)d_in[16];
  const float* W2   = (const float*)d_in[17];
  const float* b2   = (const float*)d_in[18];
  const float* fcW  = (const float*)d_in[19];
  const float* fcb  = (const float*)d_in[20];
  float* out = (float*)d_out;

  char* ws = (char*)d_ws;
  const size_t XB  = (size_t)Mx * Dx * 4;        // 104,857,600 B
  const size_t ABF = (size_t)Mx * Dx * 2;        // 52,428,800 B (full attn-out)
  const size_t WBSZ = 7340032;                   // converted-weight region

  // Preferred layout: x | q,k,v (chunked) | ab (FULL) | weights  -> oproj fused
  // into k_ffn. Fallback (tight ws): old layout with chunked ab + k_oproj.
  int nc = 0;
  for (int t = 1; t <= 32; t <<= 1) {
    size_t q3 = 3 * ((size_t)(Bx / t) * 51200);
    if (XB + q3 + ABF + WBSZ <= ws_size) { nc = t; break; }
  }
  const bool fused = (nc != 0);
  if (!fused) nc = 4;
  const int BC = Bx / nc;
  const size_t qsz = (size_t)BC * 51200;

  float* x    = (float*)ws;
  u16* qb     = (u16*)(ws + XB);
  u16* kb     = (u16*)(ws + XB + qsz);
  u16* vb     = (u16*)(ws + XB + 2 * qsz);
  u16* ab     = (u16*)(ws + XB + 3 * qsz);       // full-size if fused, chunk if not
  float* part = (float*)(ws + XB);               // aliases q/k/v/ab (dead by k_fc)
  char* WB    = fused ? (ws + XB + 3 * qsz + ABF) : (ws + XB + 4 * qsz);
  u16* W1s0   = (u16*)(WB);
  u16* W1s1   = (u16*)(WB + 131072);
  u16* W2s0   = (u16*)(WB + 262144);
  u16* W2s1   = (u16*)(WB + 393216);
  u16* Wos0   = (u16*)(WB + 524288);
  u16* Wos1   = (u16*)(WB + 557056);
  u16* Wqkvs0 = (u16*)(WB + 589824);
  u16* Wqkvs1 = (u16*)(WB + 688128);
  u16* fcWs   = (u16*)(WB + 786432);

  // ---- merged weight conversion: ONE launch for all 13 tensors ----
  CvtJobs J;
  const float* srcs[13] = {W1, W1 + Dx * FFx, W2, W2 + FFx * Dx,
                           Wo, Wo + Dx * Dx,
                           Wq, Wk, Wv,
                           Wq + Dx * Dx, Wk + Dx * Dx, Wv + Dx * Dx,
                           fcW};
  u16* dsts[13] = {W1s0, W1s1, W2s0, W2s1, Wos0, Wos1,
                   Wqkvs0, Wqkvs0 + 16384, Wqkvs0 + 32768,
                   Wqkvs1, Wqkvs1 + 16384, Wqkvs1 + 32768,
                   fcWs};
  const int Ns[13]  = {FFx, FFx, Dx, Dx, Dx, Dx, Dx, Dx, Dx, Dx, Dx, Dx, Dx};
  const int kss[13] = {4, 4, 16, 16, 4, 4, 4, 4, 4, 4, 4, 4, 800};
  const int nblk[13] = {32, 32, 32, 32, 8, 8, 8, 8, 8, 8, 8, 8, 1600};
  int acc = 0;
  for (int j = 0; j < 13; ++j) {
    J.src[j] = srcs[j]; J.dst[j] = dsts[j]; J.N[j] = Ns[j]; J.ks[j] = kss[j];
    J.bstart[j] = acc; acc += nblk[j];
  }
  J.bstart[13] = acc;   // 1792
  k_cvt_all<<<acc, 256, 0, stream>>>(J);

  k_embed<<<25600, 256, 0, stream>>>(seq, tok, pos, x);
  const int cblk = BC * 200 / 64;   // 64-row blocks per chunk
  for (int i = 0; i < 2; ++i) {
    const u16* Wqkvs = (i == 0) ? Wqkvs0 : Wqkvs1;
    const u16* Wos   = (i == 0) ? Wos0 : Wos1;
    for (int c = 0; c < nc; ++c) {
      float* xc = x + (size_t)c * BC * 200 * 128;
      const int* seqc = seq + (size_t)c * BC * 200;
      k_qkv<<<cblk, 256, 0, stream>>>(xc, ln1w + i * Dx, ln1b + i * Dx, Wqkvs,
                                      bq + i * Dx, bk + i * Dx, bv + i * Dx,
                                      qb, kb, vb);
      u16* abc = fused ? ab + (size_t)c * BC * 200 * 128 : ab;
      k_attn2<<<BC * 4, 256, 0, stream>>>(qb, kb, vb, seqc, abc);
      if (!fused)
        k_oproj<<<cblk, 256, 0, stream>>>(ab, Wos, bo + i * Dx, xc);
    }
    k_ffn<<<3200, 256, 0, stream>>>(x, fused ? ab : nullptr, Wos, bo + i * Dx,
                                    ln2w + i * Dx, ln2b + i * Dx,
                                    (i == 0) ? W1s0 : W1s1, b1 + i * FFx,
                                    (i == 0) ? W2s0 : W2s1, b2 + i * Dx);
  }
  k_fc<<<dim3(16, 32), 256, 0, stream>>>(x, fcWs, part);
  k_fcred<<<512, 256, 0, stream>>>(part, fcb, out);
}

// Round 14
// 873.499 us; speedup vs baseline: 1.1826x; 1.1413x over previous
//
#include <hip/hip_runtime.h>
#include <math.h>

typedef unsigned short u16;
typedef unsigned int u32;
typedef __attribute__((ext_vector_type(8))) short bf16x8;
typedef __attribute__((ext_vector_type(4))) float f32x4;

#define Bx 1024
#define Lx 200
#define Dx 128
#define FFx 512
#define Mx (Bx*Lx)
#define PVP 232   // P/V^T LDS row stride (u16)
#define TSP 40    // ts row stride (u16): 32 cols + 8 pad; 2-way pattern (free)

__device__ __forceinline__ u16 f2bf(float f) {
  u32 u = __float_as_uint(f);
  u32 r = (u + 0x7fffu + ((u >> 16) & 1u)) >> 16;
  return (u16)r;
}

// fast GELU: tanh form, v*sigmoid(1.59577v + 0.0713548 v^3).
// |err| vs exact erf-gelu < 1e-4 for |v|<2 (pre-act sigma~0.23) — below bf16 eps.
__device__ __forceinline__ float gelu_f(float v) {
  float z = v * fmaf(v * v, 0.0713548163f, 1.5957691216f);
  float e = __expf(-z);
  return v * __builtin_amdgcn_rcpf(1.0f + e);
}

union BFCV { u32 u[4]; bf16x8 h; };

// ---------------- merged weight convert: fp32 [K][N] -> bf16 fragment order -------
struct CvtJobs {
  const float* src[13];
  u16* dst[13];
  int N[13];
  int ks[13];
  int bstart[14];
};

__global__ void k_cvt_all(CvtJobs J) {
  const int b = blockIdx.x;
  int j = 0;
  #pragma unroll 1
  while (b >= J.bstart[j + 1]) ++j;          // uniform per block (scalar)
  const float* __restrict__ src = J.src[j];
  u16* __restrict__ dst = J.dst[j];
  const int N = J.N[j], k_steps = J.ks[j];
  int id = (b - J.bstart[j]) * 256 + threadIdx.x;
  int lane = id & 63;
  int rest = id >> 6;
  int kst = rest % k_steps;
  int ntile = rest / k_steps;
  int n = ntile * 16 + (lane & 15);
  int kb = kst * 32 + ((lane >> 4) << 3);
  const float* sp = src + (size_t)kb * N + n;
  u32 w[4];
  #pragma unroll
  for (int jj = 0; jj < 4; ++jj) {
    u32 lo = f2bf(sp[(size_t)(2 * jj) * N]);
    u32 hi = f2bf(sp[(size_t)(2 * jj + 1) * N]);
    w[jj] = lo | (hi << 16);
  }
  ((uint4*)dst)[id] = make_uint4(w[0], w[1], w[2], w[3]);
}

// ---------------- embedding: x = tok[seq] + pos ----------------
__global__ void k_embed(const int* __restrict__ seq, const float* __restrict__ tok,
                        const float* __restrict__ pos, float* __restrict__ x) {
  const int i = blockIdx.x * 256 + threadIdx.x;
  const int row = i >> 5, c = i & 31;
  const int t = seq[row];
  const int l = row % Lx;
  const float4 a = ((const float4*)tok)[(size_t)t * 32 + c];
  const float4 p = ((const float4*)pos)[l * 32 + c];
  ((float4*)x)[i] = make_float4(a.x + p.x, a.y + p.y, a.z + p.z, a.w + p.w);
}

// ---- register layernorm: lane (quad,l15) owns one row; row stats reduced across
// the 4 quad-lanes via shfl_xor(16/32). Packs af[] A-frags.
__device__ __forceinline__ void reg_ln(const float* __restrict__ xr,
                                       const float* __restrict__ ln_w,
                                       const float* __restrict__ ln_b,
                                       int quad, bf16x8 af[4]) {
  float v[32];
  float s = 0.f, sq = 0.f;
  #pragma unroll
  for (int kst = 0; kst < 4; ++kst) {
    float4 a = *(const float4*)(xr + kst * 32);
    float4 b = *(const float4*)(xr + kst * 32 + 4);
    v[kst * 8 + 0] = a.x; v[kst * 8 + 1] = a.y; v[kst * 8 + 2] = a.z; v[kst * 8 + 3] = a.w;
    v[kst * 8 + 4] = b.x; v[kst * 8 + 5] = b.y; v[kst * 8 + 6] = b.z; v[kst * 8 + 7] = b.w;
  }
  #pragma unroll
  for (int i = 0; i < 32; ++i) { s += v[i]; sq = fmaf(v[i], v[i], sq); }
  s  += __shfl_xor(s, 16);  s  += __shfl_xor(s, 32);
  sq += __shfl_xor(sq, 16); sq += __shfl_xor(sq, 32);
  float mu = s * 0.0078125f;
  float rr = rsqrtf(fmaf(-mu, mu, sq * 0.0078125f) + 1e-5f);
  #pragma unroll
  for (int kst = 0; kst < 4; ++kst) {
    const float* lwp = ln_w + kst * 32 + quad * 8;
    const float* lbp = ln_b + kst * 32 + quad * 8;
    float4 lw0 = *(const float4*)(lwp);
    float4 lw1 = *(const float4*)(lwp + 4);
    float4 lb0 = *(const float4*)(lbp);
    float4 lb1 = *(const float4*)(lbp + 4);
    float hw[8] = {lw0.x, lw0.y, lw0.z, lw0.w, lw1.x, lw1.y, lw1.z, lw1.w};
    float hb[8] = {lb0.x, lb0.y, lb0.z, lb0.w, lb1.x, lb1.y, lb1.z, lb1.w};
    BFCV cv;
    #pragma unroll
    for (int j = 0; j < 4; ++j) {
      float h0 = fmaf((v[kst * 8 + 2 * j]     - mu) * rr, hw[2 * j],     hb[2 * j]);
      float h1 = fmaf((v[kst * 8 + 2 * j + 1] - mu) * rr, hw[2 * j + 1], hb[2 * j + 1]);
      cv.u[j] = (u32)f2bf(h0) | ((u32)f2bf(h1) << 16);
    }
    af[kst] = cv.h;
  }
}

// ---------------- fused LN + QKV GEMM (MFMA), register LN, no LDS ----------------
__global__ __launch_bounds__(256, 4)
void k_qkv(const float* __restrict__ x, const float* __restrict__ ln_w,
           const float* __restrict__ ln_b, const u16* __restrict__ Wqkvs,
           const float* __restrict__ bq, const float* __restrict__ bk,
           const float* __restrict__ bv,
           u16* __restrict__ qo, u16* __restrict__ ko, u16* __restrict__ vo) {
  const int tid = threadIdx.x;
  const int row0 = blockIdx.x * 64;
  const int lane = tid & 63, wv = tid >> 6;
  const int l15 = lane & 15, quad = lane >> 4;
  const int m0 = wv * 16;

  bf16x8 af[4];
  reg_ln(x + (size_t)(row0 + m0 + l15) * Dx + quad * 8, ln_w, ln_b, quad, af);

  int bl[4], ll[4];
  #pragma unroll
  for (int r = 0; r < 4; ++r) {
    int gr = row0 + m0 + quad * 4 + r;
    bl[r] = gr / 200;
    ll[r] = gr - bl[r] * 200;
  }

  const float scale = 0.17677669529663687f;
  #pragma unroll
  for (int nt = 0; nt < 24; ++nt) {
    f32x4 acc = (f32x4){0.f, 0.f, 0.f, 0.f};
    const u16* wb = Wqkvs + ((size_t)(nt * 4) * 64 + lane) * 8;
    #pragma unroll
    for (int kst = 0; kst < 4; ++kst) {
      bf16x8 bfr = *(const bf16x8*)(wb + kst * 64 * 8);
      acc = __builtin_amdgcn_mfma_f32_16x16x32_bf16(af[kst], bfr, acc, 0, 0, 0);
    }
    const int col = (nt & 7) * 16 + l15;
    const int head = col >> 5, dk = col & 31;
    if (nt < 8) {
      float bb = bq[col];
      #pragma unroll
      for (int r = 0; r < 4; ++r)
        qo[((size_t)(bl[r] * 4 + head) * 200 + ll[r]) * 32 + dk] = f2bf((acc[r] + bb) * scale);
    } else if (nt < 16) {
      float bb = bk[col];
      #pragma unroll
      for (int r = 0; r < 4; ++r)
        ko[((size_t)(bl[r] * 4 + head) * 200 + ll[r]) * 32 + dk] = f2bf(acc[r] + bb);
    } else {
      float bb = bv[col];
      #pragma unroll
      for (int r = 0; r < 4; ++r)
        vo[((size_t)(bl[r] * 4 + head) * 200 + ll[r]) * 32 + dk] = f2bf(acc[r] + bb);
    }
  }
}

// ---------------- MFMA attention: one block per (b_local, head) ----------------
__global__ __launch_bounds__(256, 3)
void k_attn2(const u16* __restrict__ q, const u16* __restrict__ k,
             const u16* __restrict__ v, const int* __restrict__ seq,
             u16* __restrict__ attn) {
  __shared__ float smask[224];
  __shared__ __align__(16) u16 vt[32 * PVP];
  __shared__ __align__(16) u16 Pb[4][16 * PVP];
  const int tid = threadIdx.x;
  const int bl = blockIdx.x >> 2, head = blockIdx.x & 3;
  const int bh = blockIdx.x;
  const int lane = tid & 63, wv = tid >> 6;
  const int l15 = lane & 15, quad = lane >> 4;

  if (tid < 224)
    smask[tid] = (tid < 200 && seq[bl * 200 + tid] > 0) ? 0.f : -1e9f;
  // stage V^T into LDS: vt[dk][l]
  #pragma unroll 1
  for (int e = tid; e < 800; e += 256) {
    int l = e >> 2, g = (e & 3) * 8;
    uint4 pv = *(const uint4*)(v + ((size_t)bh * 200 + l) * 32 + g);
    const u16* pw = (const u16*)&pv;
    #pragma unroll
    for (int j = 0; j < 8; ++j) vt[(g + j) * PVP + l] = pw[j];
  }
  // zero V^T pad cols [200,232)
  #pragma unroll 1
  for (int e = tid; e < 1024; e += 256) {
    int rr = e >> 5, cc = 200 + (e & 31);
    vt[rr * PVP + cc] = 0;
  }
  __syncthreads();

  float msk[14];
  #pragma unroll
  for (int nt = 0; nt < 14; ++nt) msk[nt] = smask[nt * 16 + l15];

  const u16* qbase = q + (size_t)bh * 200 * 32;
  const u16* kbase = k + (size_t)bh * 200 * 32;
  u16* Pw = Pb[wv];

  #pragma unroll 1
  for (int mt = wv; mt < 13; mt += 4) {
    bf16x8 qf = *(const bf16x8*)(qbase + (mt * 16 + l15) * 32 + quad * 8);
    f32x4 s[14];
    #pragma unroll
    for (int nt = 0; nt < 14; ++nt) {
      bf16x8 kf = *(const bf16x8*)(kbase + (nt * 16 + l15) * 32 + quad * 8);
      s[nt] = __builtin_amdgcn_mfma_f32_16x16x32_bf16(qf, kf, (f32x4){0.f, 0.f, 0.f, 0.f}, 0, 0, 0);
    }
    // mask + row max
    float rmax[4] = {-1e30f, -1e30f, -1e30f, -1e30f};
    #pragma unroll
    for (int nt = 0; nt < 14; ++nt) {
      #pragma unroll
      for (int r = 0; r < 4; ++r) {
        s[nt][r] += msk[nt];
        rmax[r] = fmaxf(rmax[r], s[nt][r]);
      }
    }
    #pragma unroll
    for (int m = 1; m < 16; m <<= 1) {
      #pragma unroll
      for (int r = 0; r < 4; ++r) rmax[r] = fmaxf(rmax[r], __shfl_xor(rmax[r], m));
    }
    // exp + row sum
    float rsum[4] = {0.f, 0.f, 0.f, 0.f};
    #pragma unroll
    for (int nt = 0; nt < 14; ++nt) {
      #pragma unroll
      for (int r = 0; r < 4; ++r) {
        float p = __expf(s[nt][r] - rmax[r]);
        s[nt][r] = p;
        rsum[r] += p;
      }
    }
    #pragma unroll
    for (int m = 1; m < 16; m <<= 1) {
      #pragma unroll
      for (int r = 0; r < 4; ++r) rsum[r] += __shfl_xor(rsum[r], m);
    }
    float inv[4];
    #pragma unroll
    for (int r = 0; r < 4; ++r) inv[r] = 1.0f / rsum[r];
    // P -> wave-private LDS (bf16, unnormalized)
    #pragma unroll
    for (int nt = 0; nt < 14; ++nt) {
      #pragma unroll
      for (int r = 0; r < 4; ++r)
        Pw[(quad * 4 + r) * PVP + nt * 16 + l15] = f2bf(s[nt][r]);
    }
    __asm__ __volatile__("s_waitcnt lgkmcnt(0)" ::: "memory");
    // O = P @ V
    f32x4 o0 = (f32x4){0.f, 0.f, 0.f, 0.f}, o1 = (f32x4){0.f, 0.f, 0.f, 0.f};
    #pragma unroll
    for (int kst = 0; kst < 7; ++kst) {
      bf16x8 pf  = *(const bf16x8*)&Pw[l15 * PVP + kst * 32 + quad * 8];
      bf16x8 vf0 = *(const bf16x8*)&vt[l15 * PVP + kst * 32 + quad * 8];
      bf16x8 vf1 = *(const bf16x8*)&vt[(16 + l15) * PVP + kst * 32 + quad * 8];
      o0 = __builtin_amdgcn_mfma_f32_16x16x32_bf16(pf, vf0, o0, 0, 0, 0);
      o1 = __builtin_amdgcn_mfma_f32_16x16x32_bf16(pf, vf1, o1, 0, 0, 0);
    }
    #pragma unroll
    for (int r = 0; r < 4; ++r) {
      int row = mt * 16 + quad * 4 + r;
      if (row < 200) {
        u16* op = attn + ((size_t)bl * 200 + row) * 128 + head * 32;
        op[l15]      = f2bf(o0[r] * inv[r]);
        op[16 + l15] = f2bf(o1[r] * inv[r]);
      }
    }
  }
}

// ---------------- O-projection + residual (MFMA): x += a @ Wo + bo ----------------
// (fallback path only — used when workspace can't hold a full-size ab buffer)
__global__ __launch_bounds__(256, 4)
void k_oproj(const u16* __restrict__ a, const u16* __restrict__ Wos,
             const float* __restrict__ bo, float* __restrict__ x) {
  const int tid = threadIdx.x;
  const int lane = tid & 63, wv = tid >> 6;
  const int l15 = lane & 15, quad = lane >> 4;
  const size_t m0 = (size_t)blockIdx.x * 64 + wv * 16;
  f32x4 acc[8];
  #pragma unroll
  for (int i = 0; i < 8; ++i) acc[i] = (f32x4){0.f, 0.f, 0.f, 0.f};
  #pragma unroll
  for (int kst = 0; kst < 4; ++kst) {
    bf16x8 af = *(const bf16x8*)(a + (m0 + l15) * Dx + kst * 32 + quad * 8);
    const u16* wb = Wos + (kst * 64 + lane) * 8;
    #pragma unroll
    for (int nt = 0; nt < 8; ++nt) {
      bf16x8 bf = *(const bf16x8*)(wb + nt * (4 * 64 * 8));
      acc[nt] = __builtin_amdgcn_mfma_f32_16x16x32_bf16(af, bf, acc[nt], 0, 0, 0);
    }
  }
  #pragma unroll
  for (int nt = 0; nt < 8; ++nt) {
    int col = nt * 16 + l15;
    float bb = bo[col];
    #pragma unroll
    for (int r = 0; r < 4; ++r) {
      size_t idx = (m0 + quad * 4 + r) * Dx + col;
      x[idx] += acc[nt][r] + bb;
    }
  }
}

// ------- fused [oproj + residual + LN] + FFN (MFMA) -------
// Fused path (abp != nullptr): phase 0 computes x_new = x + ab@Wo + bo INTO acc2
// (W2-GEMM C-operand; epilogue is a plain store — no RMW). LN from acc2 registers
// (stats via shfl_xor across the quad's 16 l15-lanes). The C->A transpose of the
// normalized h runs in FOUR 32-col passes through the existing ts[64][40] slice
// (wave-private rows, lgkmcnt fences, no barrier) — r13's one-shot hs[64][136]
// pushed LDS to 50 KB and dropped residency 3->2 blocks/CU (208 us). LDS = 37888 B
// (same as verified r11) -> 3 blocks/CU.
__global__ __launch_bounds__(256, 4)
void k_ffn(float* __restrict__ x, const u16* __restrict__ abp,
           const u16* __restrict__ Wos, const float* __restrict__ bo,
           const float* __restrict__ ln_w, const float* __restrict__ ln_b,
           const u16* __restrict__ W1s, const float* __restrict__ b1,
           const u16* __restrict__ W2s, const float* __restrict__ b2) {
  __shared__ __align__(16) u16 smem[2560 + 8192 + 8192];
  u16* ts  = smem;            // [64][TSP=40] — LN transpose slices + gelu slices
  u16* w1b = smem + 2560;     // 2 x 4096 u16 (8 KB each)
  u16* w2b = smem + 10752;    // 2 x 4096 u16
  const int tid = threadIdx.x;
  const size_t row0 = (size_t)blockIdx.x * 64;
  const int lane = tid & 63, wv = tid >> 6;           // wv in [0,4)
  const int l15 = lane & 15, quad = lane >> 4;
  const int m0 = wv * 16;
  const int nt0 = tid >> 6, off = tid & 63;           // staging: 2 x 1KB pieces/thread

  f32x4 acc2[8];
  #pragma unroll
  for (int i = 0; i < 8; ++i) acc2[i] = (f32x4){0.f, 0.f, 0.f, 0.f};
  bf16x8 af[4];

  if (abp) {
    // ---- phase 0: oproj -> acc2 ----
    #pragma unroll
    for (int kst = 0; kst < 4; ++kst) {
      bf16x8 abf = *(const bf16x8*)(abp + (row0 + m0 + l15) * (size_t)Dx + kst * 32 + quad * 8);
      const u16* wb = Wos + (kst * 64 + lane) * 8;
      #pragma unroll
      for (int nt = 0; nt < 8; ++nt) {
        bf16x8 wf = *(const bf16x8*)(wb + nt * (4 * 64 * 8));
        acc2[nt] = __builtin_amdgcn_mfma_f32_16x16x32_bf16(abf, wf, acc2[nt], 0, 0, 0);
      }
    }
    // residual: acc2 += x_old + bo  (x_new lives ONLY in acc2)
    #pragma unroll
    for (int nt = 0; nt < 8; ++nt) {
      int col = nt * 16 + l15;
      float bb = bo[col];
      #pragma unroll
      for (int r = 0; r < 4; ++r)
        acc2[nt][r] += x[(row0 + m0 + quad * 4 + r) * (size_t)Dx + col] + bb;
    }
    // in-register LN stats: rows m0+quad*4+r, reduce over 8 nt + 16 l15-lanes
    float s[4] = {0.f, 0.f, 0.f, 0.f}, sq[4] = {0.f, 0.f, 0.f, 0.f};
    #pragma unroll
    for (int nt = 0; nt < 8; ++nt)
      #pragma unroll
      for (int r = 0; r < 4; ++r) {
        float v = acc2[nt][r];
        s[r] += v;
        sq[r] = fmaf(v, v, sq[r]);
      }
    #pragma unroll
    for (int m = 1; m < 16; m <<= 1) {
      #pragma unroll
      for (int r = 0; r < 4; ++r) {
        s[r]  += __shfl_xor(s[r], m);
        sq[r] += __shfl_xor(sq[r], m);
      }
    }
    float mu[4], rr[4];
    #pragma unroll
    for (int r = 0; r < 4; ++r) {
      mu[r] = s[r] * 0.0078125f;
      rr[r] = rsqrtf(fmaf(-mu[r], mu[r], sq[r] * 0.0078125f) + 1e-5f);
    }
    // C->A transpose of h, 4 passes of 32 cols through ts (wave-private rows)
    #pragma unroll
    for (int kst = 0; kst < 4; ++kst) {
      #pragma unroll
      for (int q2 = 0; q2 < 2; ++q2) {
        const int nt = 2 * kst + q2;
        const int col = nt * 16 + l15;
        float lw = ln_w[col], lb = ln_b[col];
        #pragma unroll
        for (int r = 0; r < 4; ++r)
          ts[(m0 + quad * 4 + r) * TSP + q2 * 16 + l15] =
              f2bf(fmaf((acc2[nt][r] - mu[r]) * rr[r], lw, lb));
      }
      __asm__ __volatile__("s_waitcnt lgkmcnt(0)" ::: "memory");
      af[kst] = *(const bf16x8*)&ts[(m0 + l15) * TSP + quad * 8];
      __asm__ __volatile__("s_waitcnt lgkmcnt(0)" ::: "memory");  // read done before next overwrite
    }
  } else {
    reg_ln(x + (row0 + m0 + l15) * (size_t)Dx + quad * 8, ln_w, ln_b, quad, af);
  }

  // prologue: stage W1(ch0,kst0) and W2(ch0,p0) — 8 KB each, 2 uint4/thread
  ((uint4*)w1b)[tid]       = ((const uint4*)(W1s + (size_t)(nt0 * 4) * 512))[off];
  ((uint4*)w1b)[tid + 256] = ((const uint4*)(W1s + (size_t)((nt0 + 4) * 4) * 512))[off];
  ((uint4*)w2b)[tid]       = ((const uint4*)(W2s + (size_t)(nt0 * 16) * 512))[off];
  ((uint4*)w2b)[tid + 256] = ((const uint4*)(W2s + (size_t)((nt0 + 4) * 16) * 512))[off];
  __syncthreads();

  #pragma unroll 1
  for (int ch = 0; ch < 4; ++ch) {
    // ---- GEMM1: 4 kst phases, dbuf, async-split staging ----
    f32x4 acc1[8];
    #pragma unroll
    for (int i = 0; i < 8; ++i) acc1[i] = (f32x4){0.f, 0.f, 0.f, 0.f};
    #pragma unroll
    for (int kst = 0; kst < 4; ++kst) {
      uint4 s0, s1;
      if (kst < 3) {
        s0 = ((const uint4*)(W1s + (size_t)((ch * 8 + nt0) * 4 + kst + 1) * 512))[off];
        s1 = ((const uint4*)(W1s + (size_t)((ch * 8 + nt0 + 4) * 4 + kst + 1) * 512))[off];
      }
      const u16* wb = w1b + (kst & 1) * 4096;
      #pragma unroll
      for (int nt = 0; nt < 8; ++nt) {
        bf16x8 bfr = *(const bf16x8*)&wb[nt * 512 + lane * 8];
        acc1[nt] = __builtin_amdgcn_mfma_f32_16x16x32_bf16(af[kst], bfr, acc1[nt], 0, 0, 0);
      }
      if (kst < 3) {
        uint4* d = (uint4*)(w1b + ((kst + 1) & 1) * 4096);
        d[tid] = s0; d[tid + 256] = s1;
      }
      __syncthreads();
    }
    // ---- GELU + GEMM2: 4 p phases; gelu slice p feeds kst p ----
    #pragma unroll
    for (int p = 0; p < 4; ++p) {
      uint4 s0, s1, t0, t1;
      const bool s2  = (p < 3);
      const bool s1n = (p == 3) && (ch < 3);
      if (s2) {
        s0 = ((const uint4*)(W2s + (size_t)(nt0 * 16 + ch * 4 + p + 1) * 512))[off];
        s1 = ((const uint4*)(W2s + (size_t)((nt0 + 4) * 16 + ch * 4 + p + 1) * 512))[off];
      }
      if (s1n) {
        s0 = ((const uint4*)(W1s + (size_t)(((ch + 1) * 8 + nt0) * 4) * 512))[off];
        s1 = ((const uint4*)(W1s + (size_t)(((ch + 1) * 8 + nt0 + 4) * 4) * 512))[off];
        t0 = ((const uint4*)(W2s + (size_t)(nt0 * 16 + (ch + 1) * 4) * 512))[off];
        t1 = ((const uint4*)(W2s + (size_t)((nt0 + 4) * 16 + (ch + 1) * 4) * 512))[off];
      }
      // GELU slice p (cols p*32..p*32+32 of this ch) -> ts, wave-private rows
      #pragma unroll
      for (int q2 = 0; q2 < 2; ++q2) {
        const int ntg = 2 * p + q2;
        float bb = b1[ch * 128 + ntg * 16 + l15];
        #pragma unroll
        for (int r = 0; r < 4; ++r)
          ts[(m0 + quad * 4 + r) * TSP + q2 * 16 + l15] =
              f2bf(gelu_f(acc1[ntg][r] + bb));
      }
      __asm__ __volatile__("s_waitcnt lgkmcnt(0)" ::: "memory");
      bf16x8 tf = *(const bf16x8*)&ts[(m0 + l15) * TSP + quad * 8];
      const u16* wb = w2b + (p & 1) * 4096;
      #pragma unroll
      for (int nt = 0; nt < 8; ++nt) {
        bf16x8 bfr = *(const bf16x8*)&wb[nt * 512 + lane * 8];
        acc2[nt] = __builtin_amdgcn_mfma_f32_16x16x32_bf16(tf, bfr, acc2[nt], 0, 0, 0);
      }
      if (s2) {
        uint4* d = (uint4*)(w2b + ((p + 1) & 1) * 4096);
        d[tid] = s0; d[tid + 256] = s1;
      }
      if (s1n) {
        ((uint4*)w1b)[tid] = s0; ((uint4*)w1b)[tid + 256] = s1;
        ((uint4*)w2b)[tid] = t0; ((uint4*)w2b)[tid + 256] = t1;
      }
      __syncthreads();
    }
  }
  #pragma unroll
  for (int nt = 0; nt < 8; ++nt) {
    int col = nt * 16 + l15;
    float bb = b2[col];
    #pragma unroll
    for (int r = 0; r < 4; ++r) {
      size_t idx = (row0 + m0 + quad * 4 + r) * Dx + col;
      if (abp) x[idx] = acc2[nt][r] + bb;    // acc2 carries x_new
      else     x[idx] += acc2[nt][r] + bb;
    }
  }
}

// ---------------- final FC (MFMA, split-K 32) ----------------
__global__ __launch_bounds__(256, 4)
void k_fc(const float* __restrict__ x, const u16* __restrict__ fcWs,
          float* __restrict__ part) {
  const int tid = threadIdx.x;
  const int lane = tid & 63, wv = tid >> 6;
  const int l15 = lane & 15, quad = lane >> 4;
  const int m0 = blockIdx.x * 64 + wv * 16;
  const int ky = blockIdx.y;
  f32x4 acc[8];
  #pragma unroll
  for (int i = 0; i < 8; ++i) acc[i] = (f32x4){0.f, 0.f, 0.f, 0.f};
  const float* xp = x + (size_t)(m0 + l15) * 25600 + quad * 8;
  #pragma unroll 1
  for (int kst = ky * 25; kst < ky * 25 + 25; ++kst) {
    float4 xa = *(const float4*)(xp + kst * 32);
    float4 xb2 = *(const float4*)(xp + kst * 32 + 4);
    bf16x8 af;
    af[0] = (short)f2bf(xa.x);  af[1] = (short)f2bf(xa.y);
    af[2] = (short)f2bf(xa.z);  af[3] = (short)f2bf(xa.w);
    af[4] = (short)f2bf(xb2.x); af[5] = (short)f2bf(xb2.y);
    af[6] = (short)f2bf(xb2.z); af[7] = (short)f2bf(xb2.w);
    const u16* wb = fcWs + ((size_t)kst * 64 + lane) * 8;
    #pragma unroll
    for (int nt = 0; nt < 8; ++nt) {
      bf16x8 bf = *(const bf16x8*)(wb + (size_t)nt * (800 * 64 * 8));
      acc[nt] = __builtin_amdgcn_mfma_f32_16x16x32_bf16(af, bf, acc[nt], 0, 0, 0);
    }
  }
  float* pp = part + (size_t)ky * (Bx * Dx);
  #pragma unroll
  for (int nt = 0; nt < 8; ++nt) {
    #pragma unroll
    for (int r = 0; r < 4; ++r) {
      pp[(size_t)(m0 + quad * 4 + r) * Dx + nt * 16 + l15] = acc[nt][r];
    }
  }
}

__global__ void k_fcred(const float* __restrict__ part, const float* __restrict__ fcb,
                        float* __restrict__ out) {
  int i = blockIdx.x * 256 + threadIdx.x;
  float s = fcb[i & 127];
  #pragma unroll
  for (int k = 0; k < 32; ++k) s += part[(size_t)k * (Bx * Dx) + i];
  out[i] = s;
}

extern "C" void kernel_launch(void* const* d_in, const int* in_sizes, int n_in,
                              void* d_out, int out_size, void* d_ws, size_t ws_size,
                              hipStream_t stream) {
  const int*   seq  = (const int*)d_in[0];
  const float* tok  = (const float*)d_in[1];
  const float* pos  = (const float*)d_in[2];
  const float* Wq   = (const float*)d_in[3];
  const float* bq   = (const float*)d_in[4];
  const float* Wk   = (const float*)d_in[5];
  const float* bk   = (const float*)d_in[6];
  const float* Wv   = (const float*)d_in[7];
  const float* bv   = (const float*)d_in[8];
  const float* Wo   = (const float*)d_in[9];
  const float* bo   = (const float*)d_in[10];
  const float* ln1w = (const float*)d_in[11];
  const float* ln1b = (const float*)d_in[12];
  const float* ln2w = (const float*)d_in[13];
  const float* ln2b = (const float*)d_in[14];
  const float* W1   = (const float*)d_in[15];
  const float* b1   = (const float*)d_in[16];
  const float* W2   = (const float*)d_in[17];
  const float* b2   = (const float*)d_in[18];
  const float* fcW  = (const float*)d_in[19];
  const float* fcb  = (const float*)d_in[20];
  float* out = (float*)d_out;

  char* ws = (char*)d_ws;
  const size_t XB  = (size_t)Mx * Dx * 4;        // 104,857,600 B
  const size_t ABF = (size_t)Mx * Dx * 2;        // 52,428,800 B (full attn-out)
  const size_t WBSZ = 7340032;                   // converted-weight region

  // Preferred layout: x | q,k,v (chunked) | ab (FULL) | weights  -> oproj fused
  // into k_ffn. Fallback (tight ws): old layout with chunked ab + k_oproj.
  int nc = 0;
  for (int t = 1; t <= 32; t <<= 1) {
    size_t q3 = 3 * ((size_t)(Bx / t) * 51200);
    if (XB + q3 + ABF + WBSZ <= ws_size) { nc = t; break; }
  }
  const bool fused = (nc != 0);
  if (!fused) nc = 4;
  const int BC = Bx / nc;
  const size_t qsz = (size_t)BC * 51200;

  float* x    = (float*)ws;
  u16* qb     = (u16*)(ws + XB);
  u16* kb     = (u16*)(ws + XB + qsz);
  u16* vb     = (u16*)(ws + XB + 2 * qsz);
  u16* ab     = (u16*)(ws + XB + 3 * qsz);       // full-size if fused, chunk if not
  float* part = (float*)(ws + XB);               // aliases q/k/v/ab (dead by k_fc)
  char* WB    = fused ? (ws + XB + 3 * qsz + ABF) : (ws + XB + 4 * qsz);
  u16* W1s0   = (u16*)(WB);
  u16* W1s1   = (u16*)(WB + 131072);
  u16* W2s0   = (u16*)(WB + 262144);
  u16* W2s1   = (u16*)(WB + 393216);
  u16* Wos0   = (u16*)(WB + 524288);
  u16* Wos1   = (u16*)(WB + 557056);
  u16* Wqkvs0 = (u16*)(WB + 589824);
  u16* Wqkvs1 = (u16*)(WB + 688128);
  u16* fcWs   = (u16*)(WB + 786432);

  // ---- merged weight conversion: ONE launch for all 13 tensors ----
  CvtJobs J;
  const float* srcs[13] = {W1, W1 + Dx * FFx, W2, W2 + FFx * Dx,
                           Wo, Wo + Dx * Dx,
                           Wq, Wk, Wv,
                           Wq + Dx * Dx, Wk + Dx * Dx, Wv + Dx * Dx,
                           fcW};
  u16* dsts[13] = {W1s0, W1s1, W2s0, W2s1, Wos0, Wos1,
                   Wqkvs0, Wqkvs0 + 16384, Wqkvs0 + 32768,
                   Wqkvs1, Wqkvs1 + 16384, Wqkvs1 + 32768,
                   fcWs};
  const int Ns[13]  = {FFx, FFx, Dx, Dx, Dx, Dx, Dx, Dx, Dx, Dx, Dx, Dx, Dx};
  const int kss[13] = {4, 4, 16, 16, 4, 4, 4, 4, 4, 4, 4, 4, 800};
  const int nblk[13] = {32, 32, 32, 32, 8, 8, 8, 8, 8, 8, 8, 8, 1600};
  int acc = 0;
  for (int j = 0; j < 13; ++j) {
    J.src[j] = srcs[j]; J.dst[j] = dsts[j]; J.N[j] = Ns[j]; J.ks[j] = kss[j];
    J.bstart[j] = acc; acc += nblk[j];
  }
  J.bstart[13] = acc;   // 1792
  k_cvt_all<<<acc, 256, 0, stream>>>(J);

  k_embed<<<25600, 256, 0, stream>>>(seq, tok, pos, x);
  const int cblk = BC * 200 / 64;   // 64-row blocks per chunk
  for (int i = 0; i < 2; ++i) {
    const u16* Wqkvs = (i == 0) ? Wqkvs0 : Wqkvs1;
    const u16* Wos   = (i == 0) ? Wos0 : Wos1;
    for (int c = 0; c < nc; ++c) {
      float* xc = x + (size_t)c * BC * 200 * 128;
      const int* seqc = seq + (size_t)c * BC * 200;
      k_qkv<<<cblk, 256, 0, stream>>>(xc, ln1w + i * Dx, ln1b + i * Dx, Wqkvs,
                                      bq + i * Dx, bk + i * Dx, bv + i * Dx,
                                      qb, kb, vb);
      u16* abc = fused ? ab + (size_t)c * BC * 200 * 128 : ab;
      k_attn2<<<BC * 4, 256, 0, stream>>>(qb, kb, vb, seqc, abc);
      if (!fused)
        k_oproj<<<cblk, 256, 0, stream>>>(ab, Wos, bo + i * Dx, xc);
    }
    k_ffn<<<3200, 256, 0, stream>>>(x, fused ? ab : nullptr, Wos, bo + i * Dx,
                                    ln2w + i * Dx, ln2b + i * Dx,
                                    (i == 0) ? W1s0 : W1s1, b1 + i * FFx,
                                    (i == 0) ? W2s0 : W2s1, b2 + i * Dx);
  }
  k_fc<<<dim3(16, 32), 256, 0, stream>>>(x, fcWs, part);
  k_fcred<<<512, 256, 0, stream>>>(part, fcb, out);
}

// Round 15
// 869.353 us; speedup vs baseline: 1.1883x; 1.0048x over previous
//
#include <hip/hip_runtime.h>
#include <math.h>

typedef unsigned short u16;
typedef unsigned int u32;
typedef __attribute__((ext_vector_type(8))) short bf16x8;
typedef __attribute__((ext_vector_type(4))) float f32x4;

#define Bx 1024
#define Lx 200
#define Dx 128
#define FFx 512
#define Mx (Bx*Lx)
#define PVP 232   // P/V^T LDS row stride (u16)
#define TSP 40    // ts row stride (u16): 32 cols + 8 pad; 2-way pattern (free)

__device__ __forceinline__ u16 f2bf(float f) {
  u32 u = __float_as_uint(f);
  u32 r = (u + 0x7fffu + ((u >> 16) & 1u)) >> 16;
  return (u16)r;
}

// fast GELU: tanh form, v*sigmoid(1.59577v + 0.0713548 v^3).
// |err| vs exact erf-gelu < 1e-4 for |v|<2 (pre-act sigma~0.23) — below bf16 eps.
__device__ __forceinline__ float gelu_f(float v) {
  float z = v * fmaf(v * v, 0.0713548163f, 1.5957691216f);
  float e = __expf(-z);
  return v * __builtin_amdgcn_rcpf(1.0f + e);
}

union BFCV { u32 u[4]; bf16x8 h; };

// ---------------- merged weight convert: fp32 [K][N] -> bf16 fragment order -------
struct CvtJobs {
  const float* src[13];
  u16* dst[13];
  int N[13];
  int ks[13];
  int bstart[14];
};

__global__ void k_cvt_all(CvtJobs J) {
  const int b = blockIdx.x;
  int j = 0;
  #pragma unroll 1
  while (b >= J.bstart[j + 1]) ++j;          // uniform per block (scalar)
  const float* __restrict__ src = J.src[j];
  u16* __restrict__ dst = J.dst[j];
  const int N = J.N[j], k_steps = J.ks[j];
  int id = (b - J.bstart[j]) * 256 + threadIdx.x;
  int lane = id & 63;
  int rest = id >> 6;
  int kst = rest % k_steps;
  int ntile = rest / k_steps;
  int n = ntile * 16 + (lane & 15);
  int kb = kst * 32 + ((lane >> 4) << 3);
  const float* sp = src + (size_t)kb * N + n;
  u32 w[4];
  #pragma unroll
  for (int jj = 0; jj < 4; ++jj) {
    u32 lo = f2bf(sp[(size_t)(2 * jj) * N]);
    u32 hi = f2bf(sp[(size_t)(2 * jj + 1) * N]);
    w[jj] = lo | (hi << 16);
  }
  ((uint4*)dst)[id] = make_uint4(w[0], w[1], w[2], w[3]);
}

// ---------------- embedding: x = tok[seq] + pos ----------------
__global__ void k_embed(const int* __restrict__ seq, const float* __restrict__ tok,
                        const float* __restrict__ pos, float* __restrict__ x) {
  const int i = blockIdx.x * 256 + threadIdx.x;
  const int row = i >> 5, c = i & 31;
  const int t = seq[row];
  const int l = row % Lx;
  const float4 a = ((const float4*)tok)[(size_t)t * 32 + c];
  const float4 p = ((const float4*)pos)[l * 32 + c];
  ((float4*)x)[i] = make_float4(a.x + p.x, a.y + p.y, a.z + p.z, a.w + p.w);
}

// ---- register layernorm: lane (quad,l15) owns one row; row stats reduced across
// the 4 quad-lanes via shfl_xor(16/32). Packs af[] A-frags.
__device__ __forceinline__ void reg_ln(const float* __restrict__ xr,
                                       const float* __restrict__ ln_w,
                                       const float* __restrict__ ln_b,
                                       int quad, bf16x8 af[4]) {
  float v[32];
  float s = 0.f, sq = 0.f;
  #pragma unroll
  for (int kst = 0; kst < 4; ++kst) {
    float4 a = *(const float4*)(xr + kst * 32);
    float4 b = *(const float4*)(xr + kst * 32 + 4);
    v[kst * 8 + 0] = a.x; v[kst * 8 + 1] = a.y; v[kst * 8 + 2] = a.z; v[kst * 8 + 3] = a.w;
    v[kst * 8 + 4] = b.x; v[kst * 8 + 5] = b.y; v[kst * 8 + 6] = b.z; v[kst * 8 + 7] = b.w;
  }
  #pragma unroll
  for (int i = 0; i < 32; ++i) { s += v[i]; sq = fmaf(v[i], v[i], sq); }
  s  += __shfl_xor(s, 16);  s  += __shfl_xor(s, 32);
  sq += __shfl_xor(sq, 16); sq += __shfl_xor(sq, 32);
  float mu = s * 0.0078125f;
  float rr = rsqrtf(fmaf(-mu, mu, sq * 0.0078125f) + 1e-5f);
  #pragma unroll
  for (int kst = 0; kst < 4; ++kst) {
    const float* lwp = ln_w + kst * 32 + quad * 8;
    const float* lbp = ln_b + kst * 32 + quad * 8;
    float4 lw0 = *(const float4*)(lwp);
    float4 lw1 = *(const float4*)(lwp + 4);
    float4 lb0 = *(const float4*)(lbp);
    float4 lb1 = *(const float4*)(lbp + 4);
    float hw[8] = {lw0.x, lw0.y, lw0.z, lw0.w, lw1.x, lw1.y, lw1.z, lw1.w};
    float hb[8] = {lb0.x, lb0.y, lb0.z, lb0.w, lb1.x, lb1.y, lb1.z, lb1.w};
    BFCV cv;
    #pragma unroll
    for (int j = 0; j < 4; ++j) {
      float h0 = fmaf((v[kst * 8 + 2 * j]     - mu) * rr, hw[2 * j],     hb[2 * j]);
      float h1 = fmaf((v[kst * 8 + 2 * j + 1] - mu) * rr, hw[2 * j + 1], hb[2 * j + 1]);
      cv.u[j] = (u32)f2bf(h0) | ((u32)f2bf(h1) << 16);
    }
    af[kst] = cv.h;
  }
}

// ---------------- fused LN + QKV GEMM (MFMA), register LN, no LDS ----------------
__global__ __launch_bounds__(256, 4)
void k_qkv(const float* __restrict__ x, const float* __restrict__ ln_w,
           const float* __restrict__ ln_b, const u16* __restrict__ Wqkvs,
           const float* __restrict__ bq, const float* __restrict__ bk,
           const float* __restrict__ bv,
           u16* __restrict__ qo, u16* __restrict__ ko, u16* __restrict__ vo) {
  const int tid = threadIdx.x;
  const int row0 = blockIdx.x * 64;
  const int lane = tid & 63, wv = tid >> 6;
  const int l15 = lane & 15, quad = lane >> 4;
  const int m0 = wv * 16;

  bf16x8 af[4];
  reg_ln(x + (size_t)(row0 + m0 + l15) * Dx + quad * 8, ln_w, ln_b, quad, af);

  int bl[4], ll[4];
  #pragma unroll
  for (int r = 0; r < 4; ++r) {
    int gr = row0 + m0 + quad * 4 + r;
    bl[r] = gr / 200;
    ll[r] = gr - bl[r] * 200;
  }

  const float scale = 0.17677669529663687f;
  #pragma unroll
  for (int nt = 0; nt < 24; ++nt) {
    f32x4 acc = (f32x4){0.f, 0.f, 0.f, 0.f};
    const u16* wb = Wqkvs + ((size_t)(nt * 4) * 64 + lane) * 8;
    #pragma unroll
    for (int kst = 0; kst < 4; ++kst) {
      bf16x8 bfr = *(const bf16x8*)(wb + kst * 64 * 8);
      acc = __builtin_amdgcn_mfma_f32_16x16x32_bf16(af[kst], bfr, acc, 0, 0, 0);
    }
    const int col = (nt & 7) * 16 + l15;
    const int head = col >> 5, dk = col & 31;
    if (nt < 8) {
      float bb = bq[col];
      #pragma unroll
      for (int r = 0; r < 4; ++r)
        qo[((size_t)(bl[r] * 4 + head) * 200 + ll[r]) * 32 + dk] = f2bf((acc[r] + bb) * scale);
    } else if (nt < 16) {
      float bb = bk[col];
      #pragma unroll
      for (int r = 0; r < 4; ++r)
        ko[((size_t)(bl[r] * 4 + head) * 200 + ll[r]) * 32 + dk] = f2bf(acc[r] + bb);
    } else {
      float bb = bv[col];
      #pragma unroll
      for (int r = 0; r < 4; ++r)
        vo[((size_t)(bl[r] * 4 + head) * 200 + ll[r]) * 32 + dk] = f2bf(acc[r] + bb);
    }
  }
}

// ---------------- MFMA attention: one block per (b_local, head) ----------------
__global__ __launch_bounds__(256, 3)
void k_attn2(const u16* __restrict__ q, const u16* __restrict__ k,
             const u16* __restrict__ v, const int* __restrict__ seq,
             u16* __restrict__ attn) {
  __shared__ float smask[224];
  __shared__ __align__(16) u16 vt[32 * PVP];
  __shared__ __align__(16) u16 Pb[4][16 * PVP];
  const int tid = threadIdx.x;
  const int bl = blockIdx.x >> 2, head = blockIdx.x & 3;
  const int bh = blockIdx.x;
  const int lane = tid & 63, wv = tid >> 6;
  const int l15 = lane & 15, quad = lane >> 4;

  if (tid < 224)
    smask[tid] = (tid < 200 && seq[bl * 200 + tid] > 0) ? 0.f : -1e9f;
  // stage V^T into LDS: vt[dk][l]
  #pragma unroll 1
  for (int e = tid; e < 800; e += 256) {
    int l = e >> 2, g = (e & 3) * 8;
    uint4 pv = *(const uint4*)(v + ((size_t)bh * 200 + l) * 32 + g);
    const u16* pw = (const u16*)&pv;
    #pragma unroll
    for (int j = 0; j < 8; ++j) vt[(g + j) * PVP + l] = pw[j];
  }
  // zero V^T pad cols [200,232)
  #pragma unroll 1
  for (int e = tid; e < 1024; e += 256) {
    int rr = e >> 5, cc = 200 + (e & 31);
    vt[rr * PVP + cc] = 0;
  }
  __syncthreads();

  float msk[14];
  #pragma unroll
  for (int nt = 0; nt < 14; ++nt) msk[nt] = smask[nt * 16 + l15];

  const u16* qbase = q + (size_t)bh * 200 * 32;
  const u16* kbase = k + (size_t)bh * 200 * 32;
  u16* Pw = Pb[wv];

  #pragma unroll 1
  for (int mt = wv; mt < 13; mt += 4) {
    bf16x8 qf = *(const bf16x8*)(qbase + (mt * 16 + l15) * 32 + quad * 8);
    f32x4 s[14];
    #pragma unroll
    for (int nt = 0; nt < 14; ++nt) {
      bf16x8 kf = *(const bf16x8*)(kbase + (nt * 16 + l15) * 32 + quad * 8);
      s[nt] = __builtin_amdgcn_mfma_f32_16x16x32_bf16(qf, kf, (f32x4){0.f, 0.f, 0.f, 0.f}, 0, 0, 0);
    }
    // mask + row max
    float rmax[4] = {-1e30f, -1e30f, -1e30f, -1e30f};
    #pragma unroll
    for (int nt = 0; nt < 14; ++nt) {
      #pragma unroll
      for (int r = 0; r < 4; ++r) {
        s[nt][r] += msk[nt];
        rmax[r] = fmaxf(rmax[r], s[nt][r]);
      }
    }
    #pragma unroll
    for (int m = 1; m < 16; m <<= 1) {
      #pragma unroll
      for (int r = 0; r < 4; ++r) rmax[r] = fmaxf(rmax[r], __shfl_xor(rmax[r], m));
    }
    // exp + row sum
    float rsum[4] = {0.f, 0.f, 0.f, 0.f};
    #pragma unroll
    for (int nt = 0; nt < 14; ++nt) {
      #pragma unroll
      for (int r = 0; r < 4; ++r) {
        float p = __expf(s[nt][r] - rmax[r]);
        s[nt][r] = p;
        rsum[r] += p;
      }
    }
    #pragma unroll
    for (int m = 1; m < 16; m <<= 1) {
      #pragma unroll
      for (int r = 0; r < 4; ++r) rsum[r] += __shfl_xor(rsum[r], m);
    }
    float inv[4];
    #pragma unroll
    for (int r = 0; r < 4; ++r) inv[r] = 1.0f / rsum[r];
    // P -> wave-private LDS (bf16, unnormalized)
    #pragma unroll
    for (int nt = 0; nt < 14; ++nt) {
      #pragma unroll
      for (int r = 0; r < 4; ++r)
        Pw[(quad * 4 + r) * PVP + nt * 16 + l15] = f2bf(s[nt][r]);
    }
    __asm__ __volatile__("s_waitcnt lgkmcnt(0)" ::: "memory");
    // O = P @ V
    f32x4 o0 = (f32x4){0.f, 0.f, 0.f, 0.f}, o1 = (f32x4){0.f, 0.f, 0.f, 0.f};
    #pragma unroll
    for (int kst = 0; kst < 7; ++kst) {
      bf16x8 pf  = *(const bf16x8*)&Pw[l15 * PVP + kst * 32 + quad * 8];
      bf16x8 vf0 = *(const bf16x8*)&vt[l15 * PVP + kst * 32 + quad * 8];
      bf16x8 vf1 = *(const bf16x8*)&vt[(16 + l15) * PVP + kst * 32 + quad * 8];
      o0 = __builtin_amdgcn_mfma_f32_16x16x32_bf16(pf, vf0, o0, 0, 0, 0);
      o1 = __builtin_amdgcn_mfma_f32_16x16x32_bf16(pf, vf1, o1, 0, 0, 0);
    }
    #pragma unroll
    for (int r = 0; r < 4; ++r) {
      int row = mt * 16 + quad * 4 + r;
      if (row < 200) {
        u16* op = attn + ((size_t)bl * 200 + row) * 128 + head * 32;
        op[l15]      = f2bf(o0[r] * inv[r]);
        op[16 + l15] = f2bf(o1[r] * inv[r]);
      }
    }
  }
}

// ---------------- O-projection + residual (MFMA): x += a @ Wo + bo ----------------
// (fallback path only — used when workspace can't hold a full-size ab buffer)
__global__ __launch_bounds__(256, 4)
void k_oproj(const u16* __restrict__ a, const u16* __restrict__ Wos,
             const float* __restrict__ bo, float* __restrict__ x) {
  const int tid = threadIdx.x;
  const int lane = tid & 63, wv = tid >> 6;
  const int l15 = lane & 15, quad = lane >> 4;
  const size_t m0 = (size_t)blockIdx.x * 64 + wv * 16;
  f32x4 acc[8];
  #pragma unroll
  for (int i = 0; i < 8; ++i) acc[i] = (f32x4){0.f, 0.f, 0.f, 0.f};
  #pragma unroll
  for (int kst = 0; kst < 4; ++kst) {
    bf16x8 af = *(const bf16x8*)(a + (m0 + l15) * Dx + kst * 32 + quad * 8);
    const u16* wb = Wos + (kst * 64 + lane) * 8;
    #pragma unroll
    for (int nt = 0; nt < 8; ++nt) {
      bf16x8 bf = *(const bf16x8*)(wb + nt * (4 * 64 * 8));
      acc[nt] = __builtin_amdgcn_mfma_f32_16x16x32_bf16(af, bf, acc[nt], 0, 0, 0);
    }
  }
  #pragma unroll
  for (int nt = 0; nt < 8; ++nt) {
    int col = nt * 16 + l15;
    float bb = bo[col];
    #pragma unroll
    for (int r = 0; r < 4; ++r) {
      size_t idx = (m0 + quad * 4 + r) * Dx + col;
      x[idx] += acc[nt][r] + bb;
    }
  }
}

// ------- fused [oproj + residual + LN] + FFN (MFMA) -------
// Fused path (abp != nullptr): phase 0 computes x_new = x + ab@Wo + bo INTO acc2
// (W2-GEMM C-operand; epilogue is a plain store — no RMW). LN from acc2 registers;
// C->A transpose of h in four 32-col passes through ts[64][40] (LDS stays 37888 B
// -> 3 blocks/CU). When xbo != nullptr (last layer feeding the final FC): epilogue
// stores x_new as BF16 into xbo (same f2bf the FC did anyway — numerically
// identical) and skips the fp32 x write entirely. xbo row-aliases abp safely:
// each block reads its own ab rows (phase 0) before writing the same rows.
__global__ __launch_bounds__(256, 4)
void k_ffn(float* __restrict__ x, const u16* __restrict__ abp,
           const u16* __restrict__ Wos, const float* __restrict__ bo,
           const float* __restrict__ ln_w, const float* __restrict__ ln_b,
           const u16* __restrict__ W1s, const float* __restrict__ b1,
           const u16* __restrict__ W2s, const float* __restrict__ b2,
           u16* xbo) {
  __shared__ __align__(16) u16 smem[2560 + 8192 + 8192];
  u16* ts  = smem;            // [64][TSP=40] — LN transpose slices + gelu slices
  u16* w1b = smem + 2560;     // 2 x 4096 u16 (8 KB each)
  u16* w2b = smem + 10752;    // 2 x 4096 u16
  const int tid = threadIdx.x;
  const size_t row0 = (size_t)blockIdx.x * 64;
  const int lane = tid & 63, wv = tid >> 6;           // wv in [0,4)
  const int l15 = lane & 15, quad = lane >> 4;
  const int m0 = wv * 16;
  const int nt0 = tid >> 6, off = tid & 63;           // staging: 2 x 1KB pieces/thread

  f32x4 acc2[8];
  #pragma unroll
  for (int i = 0; i < 8; ++i) acc2[i] = (f32x4){0.f, 0.f, 0.f, 0.f};
  bf16x8 af[4];

  if (abp) {
    // ---- phase 0: oproj -> acc2 ----
    #pragma unroll
    for (int kst = 0; kst < 4; ++kst) {
      bf16x8 abf = *(const bf16x8*)(abp + (row0 + m0 + l15) * (size_t)Dx + kst * 32 + quad * 8);
      const u16* wb = Wos + (kst * 64 + lane) * 8;
      #pragma unroll
      for (int nt = 0; nt < 8; ++nt) {
        bf16x8 wf = *(const bf16x8*)(wb + nt * (4 * 64 * 8));
        acc2[nt] = __builtin_amdgcn_mfma_f32_16x16x32_bf16(abf, wf, acc2[nt], 0, 0, 0);
      }
    }
    // residual: acc2 += x_old + bo  (x_new lives ONLY in acc2)
    #pragma unroll
    for (int nt = 0; nt < 8; ++nt) {
      int col = nt * 16 + l15;
      float bb = bo[col];
      #pragma unroll
      for (int r = 0; r < 4; ++r)
        acc2[nt][r] += x[(row0 + m0 + quad * 4 + r) * (size_t)Dx + col] + bb;
    }
    // in-register LN stats: rows m0+quad*4+r, reduce over 8 nt + 16 l15-lanes
    float s[4] = {0.f, 0.f, 0.f, 0.f}, sq[4] = {0.f, 0.f, 0.f, 0.f};
    #pragma unroll
    for (int nt = 0; nt < 8; ++nt)
      #pragma unroll
      for (int r = 0; r < 4; ++r) {
        float v = acc2[nt][r];
        s[r] += v;
        sq[r] = fmaf(v, v, sq[r]);
      }
    #pragma unroll
    for (int m = 1; m < 16; m <<= 1) {
      #pragma unroll
      for (int r = 0; r < 4; ++r) {
        s[r]  += __shfl_xor(s[r], m);
        sq[r] += __shfl_xor(sq[r], m);
      }
    }
    float mu[4], rr[4];
    #pragma unroll
    for (int r = 0; r < 4; ++r) {
      mu[r] = s[r] * 0.0078125f;
      rr[r] = rsqrtf(fmaf(-mu[r], mu[r], sq[r] * 0.0078125f) + 1e-5f);
    }
    // C->A transpose of h, 4 passes of 32 cols through ts (wave-private rows)
    #pragma unroll
    for (int kst = 0; kst < 4; ++kst) {
      #pragma unroll
      for (int q2 = 0; q2 < 2; ++q2) {
        const int nt = 2 * kst + q2;
        const int col = nt * 16 + l15;
        float lw = ln_w[col], lb = ln_b[col];
        #pragma unroll
        for (int r = 0; r < 4; ++r)
          ts[(m0 + quad * 4 + r) * TSP + q2 * 16 + l15] =
              f2bf(fmaf((acc2[nt][r] - mu[r]) * rr[r], lw, lb));
      }
      __asm__ __volatile__("s_waitcnt lgkmcnt(0)" ::: "memory");
      af[kst] = *(const bf16x8*)&ts[(m0 + l15) * TSP + quad * 8];
      __asm__ __volatile__("s_waitcnt lgkmcnt(0)" ::: "memory");  // read done before next overwrite
    }
  } else {
    reg_ln(x + (row0 + m0 + l15) * (size_t)Dx + quad * 8, ln_w, ln_b, quad, af);
  }

  // prologue: stage W1(ch0,kst0) and W2(ch0,p0) — 8 KB each, 2 uint4/thread
  ((uint4*)w1b)[tid]       = ((const uint4*)(W1s + (size_t)(nt0 * 4) * 512))[off];
  ((uint4*)w1b)[tid + 256] = ((const uint4*)(W1s + (size_t)((nt0 + 4) * 4) * 512))[off];
  ((uint4*)w2b)[tid]       = ((const uint4*)(W2s + (size_t)(nt0 * 16) * 512))[off];
  ((uint4*)w2b)[tid + 256] = ((const uint4*)(W2s + (size_t)((nt0 + 4) * 16) * 512))[off];
  __syncthreads();

  #pragma unroll 1
  for (int ch = 0; ch < 4; ++ch) {
    // ---- GEMM1: 4 kst phases, dbuf, async-split staging ----
    f32x4 acc1[8];
    #pragma unroll
    for (int i = 0; i < 8; ++i) acc1[i] = (f32x4){0.f, 0.f, 0.f, 0.f};
    #pragma unroll
    for (int kst = 0; kst < 4; ++kst) {
      uint4 s0, s1;
      if (kst < 3) {
        s0 = ((const uint4*)(W1s + (size_t)((ch * 8 + nt0) * 4 + kst + 1) * 512))[off];
        s1 = ((const uint4*)(W1s + (size_t)((ch * 8 + nt0 + 4) * 4 + kst + 1) * 512))[off];
      }
      const u16* wb = w1b + (kst & 1) * 4096;
      #pragma unroll
      for (int nt = 0; nt < 8; ++nt) {
        bf16x8 bfr = *(const bf16x8*)&wb[nt * 512 + lane * 8];
        acc1[nt] = __builtin_amdgcn_mfma_f32_16x16x32_bf16(af[kst], bfr, acc1[nt], 0, 0, 0);
      }
      if (kst < 3) {
        uint4* d = (uint4*)(w1b + ((kst + 1) & 1) * 4096);
        d[tid] = s0; d[tid + 256] = s1;
      }
      __syncthreads();
    }
    // ---- GELU + GEMM2: 4 p phases; gelu slice p feeds kst p ----
    #pragma unroll
    for (int p = 0; p < 4; ++p) {
      uint4 s0, s1, t0, t1;
      const bool s2  = (p < 3);
      const bool s1n = (p == 3) && (ch < 3);
      if (s2) {
        s0 = ((const uint4*)(W2s + (size_t)(nt0 * 16 + ch * 4 + p + 1) * 512))[off];
        s1 = ((const uint4*)(W2s + (size_t)((nt0 + 4) * 16 + ch * 4 + p + 1) * 512))[off];
      }
      if (s1n) {
        s0 = ((const uint4*)(W1s + (size_t)(((ch + 1) * 8 + nt0) * 4) * 512))[off];
        s1 = ((const uint4*)(W1s + (size_t)(((ch + 1) * 8 + nt0 + 4) * 4) * 512))[off];
        t0 = ((const uint4*)(W2s + (size_t)(nt0 * 16 + (ch + 1) * 4) * 512))[off];
        t1 = ((const uint4*)(W2s + (size_t)((nt0 + 4) * 16 + (ch + 1) * 4) * 512))[off];
      }
      // GELU slice p (cols p*32..p*32+32 of this ch) -> ts, wave-private rows
      #pragma unroll
      for (int q2 = 0; q2 < 2; ++q2) {
        const int ntg = 2 * p + q2;
        float bb = b1[ch * 128 + ntg * 16 + l15];
        #pragma unroll
        for (int r = 0; r < 4; ++r)
          ts[(m0 + quad * 4 + r) * TSP + q2 * 16 + l15] =
              f2bf(gelu_f(acc1[ntg][r] + bb));
      }
      __asm__ __volatile__("s_waitcnt lgkmcnt(0)" ::: "memory");
      bf16x8 tf = *(const bf16x8*)&ts[(m0 + l15) * TSP + quad * 8];
      const u16* wb = w2b + (p & 1) * 4096;
      #pragma unroll
      for (int nt = 0; nt < 8; ++nt) {
        bf16x8 bfr = *(const bf16x8*)&wb[nt * 512 + lane * 8];
        acc2[nt] = __builtin_amdgcn_mfma_f32_16x16x32_bf16(tf, bfr, acc2[nt], 0, 0, 0);
      }
      if (s2) {
        uint4* d = (uint4*)(w2b + ((p + 1) & 1) * 4096);
        d[tid] = s0; d[tid + 256] = s1;
      }
      if (s1n) {
        ((uint4*)w1b)[tid] = s0; ((uint4*)w1b)[tid + 256] = s1;
        ((uint4*)w2b)[tid] = t0; ((uint4*)w2b)[tid + 256] = t1;
      }
      __syncthreads();
    }
  }
  #pragma unroll
  for (int nt = 0; nt < 8; ++nt) {
    int col = nt * 16 + l15;
    float bb = b2[col];
    #pragma unroll
    for (int r = 0; r < 4; ++r) {
      size_t idx = (row0 + m0 + quad * 4 + r) * Dx + col;
      float xv = acc2[nt][r] + bb;
      if (xbo)      xbo[idx] = f2bf(xv);   // bf16 for final FC; fp32 x is dead
      else if (abp) x[idx] = xv;           // acc2 carries x_new
      else          x[idx] += xv;
    }
  }
}

// ---------------- final FC (MFMA, split-K 32), fp32-x fallback ----------------
__global__ __launch_bounds__(256, 4)
void k_fc(const float* __restrict__ x, const u16* __restrict__ fcWs,
          float* __restrict__ part) {
  const int tid = threadIdx.x;
  const int lane = tid & 63, wv = tid >> 6;
  const int l15 = lane & 15, quad = lane >> 4;
  const int m0 = blockIdx.x * 64 + wv * 16;
  const int ky = blockIdx.y;
  f32x4 acc[8];
  #pragma unroll
  for (int i = 0; i < 8; ++i) acc[i] = (f32x4){0.f, 0.f, 0.f, 0.f};
  const float* xp = x + (size_t)(m0 + l15) * 25600 + quad * 8;
  #pragma unroll 1
  for (int kst = ky * 25; kst < ky * 25 + 25; ++kst) {
    float4 xa = *(const float4*)(xp + kst * 32);
    float4 xb2 = *(const float4*)(xp + kst * 32 + 4);
    bf16x8 af;
    af[0] = (short)f2bf(xa.x);  af[1] = (short)f2bf(xa.y);
    af[2] = (short)f2bf(xa.z);  af[3] = (short)f2bf(xa.w);
    af[4] = (short)f2bf(xb2.x); af[5] = (short)f2bf(xb2.y);
    af[6] = (short)f2bf(xb2.z); af[7] = (short)f2bf(xb2.w);
    const u16* wb = fcWs + ((size_t)kst * 64 + lane) * 8;
    #pragma unroll
    for (int nt = 0; nt < 8; ++nt) {
      bf16x8 bf = *(const bf16x8*)(wb + (size_t)nt * (800 * 64 * 8));
      acc[nt] = __builtin_amdgcn_mfma_f32_16x16x32_bf16(af, bf, acc[nt], 0, 0, 0);
    }
  }
  float* pp = part + (size_t)ky * (Bx * Dx);
  #pragma unroll
  for (int nt = 0; nt < 8; ++nt) {
    #pragma unroll
    for (int r = 0; r < 4; ++r) {
      pp[(size_t)(m0 + quad * 4 + r) * Dx + nt * 16 + l15] = acc[nt][r];
    }
  }
}

// ---------------- final FC (MFMA, split-K 32), bf16-x path ----------------
// x already in bf16 fragment-ready rows (written by layer-1 k_ffn) -> one 16B
// load per kst, no f2bf chain (~200 VALU/lane removed), half the x read bytes.
__global__ __launch_bounds__(256, 4)
void k_fcb(const u16* __restrict__ xb, const u16* __restrict__ fcWs,
           float* __restrict__ part) {
  const int tid = threadIdx.x;
  const int lane = tid & 63, wv = tid >> 6;
  const int l15 = lane & 15, quad = lane >> 4;
  const int m0 = blockIdx.x * 64 + wv * 16;
  const int ky = blockIdx.y;
  f32x4 acc[8];
  #pragma unroll
  for (int i = 0; i < 8; ++i) acc[i] = (f32x4){0.f, 0.f, 0.f, 0.f};
  const u16* xp = xb + (size_t)(m0 + l15) * 25600 + quad * 8;
  #pragma unroll 1
  for (int kst = ky * 25; kst < ky * 25 + 25; ++kst) {
    bf16x8 af = *(const bf16x8*)(xp + kst * 32);
    const u16* wb = fcWs + ((size_t)kst * 64 + lane) * 8;
    #pragma unroll
    for (int nt = 0; nt < 8; ++nt) {
      bf16x8 bf = *(const bf16x8*)(wb + (size_t)nt * (800 * 64 * 8));
      acc[nt] = __builtin_amdgcn_mfma_f32_16x16x32_bf16(af, bf, acc[nt], 0, 0, 0);
    }
  }
  float* pp = part + (size_t)ky * (Bx * Dx);
  #pragma unroll
  for (int nt = 0; nt < 8; ++nt) {
    #pragma unroll
    for (int r = 0; r < 4; ++r) {
      pp[(size_t)(m0 + quad * 4 + r) * Dx + nt * 16 + l15] = acc[nt][r];
    }
  }
}

__global__ void k_fcred(const float* __restrict__ part, const float* __restrict__ fcb,
                        float* __restrict__ out) {
  int i = blockIdx.x * 256 + threadIdx.x;
  float s = fcb[i & 127];
  #pragma unroll
  for (int k = 0; k < 32; ++k) s += part[(size_t)k * (Bx * Dx) + i];
  out[i] = s;
}

extern "C" void kernel_launch(void* const* d_in, const int* in_sizes, int n_in,
                              void* d_out, int out_size, void* d_ws, size_t ws_size,
                              hipStream_t stream) {
  const int*   seq  = (const int*)d_in[0];
  const float* tok  = (const float*)d_in[1];
  const float* pos  = (const float*)d_in[2];
  const float* Wq   = (const float*)d_in[3];
  const float* bq   = (const float*)d_in[4];
  const float* Wk   = (const float*)d_in[5];
  const float* bk   = (const float*)d_in[6];
  const float* Wv   = (const float*)d_in[7];
  const float* bv   = (const float*)d_in[8];
  const float* Wo   = (const float*)d_in[9];
  const float* bo   = (const float*)d_in[10];
  const float* ln1w = (const float*)d_in[11];
  const float* ln1b = (const float*)d_in[12];
  const float* ln2w = (const float*)d_in[13];
  const float* ln2b = (const float*)d_in[14];
  const float* W1   = (const float*)d_in[15];
  const float* b1   = (const float*)d_in[16];
  const float* W2   = (const float*)d_in[17];
  const float* b2   = (const float*)d_in[18];
  const float* fcW  = (const float*)d_in[19];
  const float* fcb  = (const float*)d_in[20];
  float* out = (float*)d_out;

  char* ws = (char*)d_ws;
  const size_t XB  = (size_t)Mx * Dx * 4;        // 104,857,600 B
  const size_t ABF = (size_t)Mx * Dx * 2;        // 52,428,800 B (full attn-out)
  const size_t WBSZ = 7340032;                   // converted-weight region
  const size_t PARTB = (size_t)32 * Bx * Dx * 4; // 16,777,216 B (split-K partials)

  // Preferred layout: x | q,k,v (chunked) | ab (FULL) | weights  -> oproj fused
  // into k_ffn. Fallback (tight ws): old layout with chunked ab + k_oproj.
  int nc = 0;
  for (int t = 1; t <= 32; t <<= 1) {
    size_t q3 = 3 * ((size_t)(Bx / t) * 51200);
    if (XB + q3 + ABF + WBSZ <= ws_size) { nc = t; break; }
  }
  const bool fused = (nc != 0);
  if (!fused) nc = 4;
  const int BC = Bx / nc;
  const size_t qsz = (size_t)BC * 51200;
  // bf16-x final FC: needs part (at XB, aliasing q/k/v) to not overlap ab
  const bool bffc = fused && (3 * qsz >= PARTB);

  float* x    = (float*)ws;
  u16* qb     = (u16*)(ws + XB);
  u16* kb     = (u16*)(ws + XB + qsz);
  u16* vb     = (u16*)(ws + XB + 2 * qsz);
  u16* ab     = (u16*)(ws + XB + 3 * qsz);       // full-size if fused, chunk if not
  float* part = (float*)(ws + XB);               // aliases q/k/v (dead by k_fc)
  char* WB    = fused ? (ws + XB + 3 * qsz + ABF) : (ws + XB + 4 * qsz);
  u16* W1s0   = (u16*)(WB);
  u16* W1s1   = (u16*)(WB + 131072);
  u16* W2s0   = (u16*)(WB + 262144);
  u16* W2s1   = (u16*)(WB + 393216);
  u16* Wos0   = (u16*)(WB + 524288);
  u16* Wos1   = (u16*)(WB + 557056);
  u16* Wqkvs0 = (u16*)(WB + 589824);
  u16* Wqkvs1 = (u16*)(WB + 688128);
  u16* fcWs   = (u16*)(WB + 786432);

  // ---- merged weight conversion: ONE launch for all 13 tensors ----
  CvtJobs J;
  const float* srcs[13] = {W1, W1 + Dx * FFx, W2, W2 + FFx * Dx,
                           Wo, Wo + Dx * Dx,
                           Wq, Wk, Wv,
                           Wq + Dx * Dx, Wk + Dx * Dx, Wv + Dx * Dx,
                           fcW};
  u16* dsts[13] = {W1s0, W1s1, W2s0, W2s1, Wos0, Wos1,
                   Wqkvs0, Wqkvs0 + 16384, Wqkvs0 + 32768,
                   Wqkvs1, Wqkvs1 + 16384, Wqkvs1 + 32768,
                   fcWs};
  const int Ns[13]  = {FFx, FFx, Dx, Dx, Dx, Dx, Dx, Dx, Dx, Dx, Dx, Dx, Dx};
  const int kss[13] = {4, 4, 16, 16, 4, 4, 4, 4, 4, 4, 4, 4, 800};
  const int nblk[13] = {32, 32, 32, 32, 8, 8, 8, 8, 8, 8, 8, 8, 1600};
  int acc = 0;
  for (int j = 0; j < 13; ++j) {
    J.src[j] = srcs[j]; J.dst[j] = dsts[j]; J.N[j] = Ns[j]; J.ks[j] = kss[j];
    J.bstart[j] = acc; acc += nblk[j];
  }
  J.bstart[13] = acc;   // 1792
  k_cvt_all<<<acc, 256, 0, stream>>>(J);

  k_embed<<<25600, 256, 0, stream>>>(seq, tok, pos, x);
  const int cblk = BC * 200 / 64;   // 64-row blocks per chunk
  for (int i = 0; i < 2; ++i) {
    const u16* Wqkvs = (i == 0) ? Wqkvs0 : Wqkvs1;
    const u16* Wos   = (i == 0) ? Wos0 : Wos1;
    for (int c = 0; c < nc; ++c) {
      float* xc = x + (size_t)c * BC * 200 * 128;
      const int* seqc = seq + (size_t)c * BC * 200;
      k_qkv<<<cblk, 256, 0, stream>>>(xc, ln1w + i * Dx, ln1b + i * Dx, Wqkvs,
                                      bq + i * Dx, bk + i * Dx, bv + i * Dx,
                                      qb, kb, vb);
      u16* abc = fused ? ab + (size_t)c * BC * 200 * 128 : ab;
      k_attn2<<<BC * 4, 256, 0, stream>>>(qb, kb, vb, seqc, abc);
      if (!fused)
        k_oproj<<<cblk, 256, 0, stream>>>(ab, Wos, bo + i * Dx, xc);
    }
    k_ffn<<<3200, 256, 0, stream>>>(x, fused ? ab : nullptr, Wos, bo + i * Dx,
                                    ln2w + i * Dx, ln2b + i * Dx,
                                    (i == 0) ? W1s0 : W1s1, b1 + i * FFx,
                                    (i == 0) ? W2s0 : W2s1, b2 + i * Dx,
                                    (i == 1 && bffc) ? ab : nullptr);
  }
  if (bffc)
    k_fcb<<<dim3(16, 32), 256, 0, stream>>>(ab, fcWs, part);
  else
    k_fc<<<dim3(16, 32), 256, 0, stream>>>(x, fcWs, part);
  k_fcred<<<512, 256, 0, stream>>>(part, fcb, out);
}